// Round 4
// baseline (337.434 us; speedup 1.0000x reference)
//
#include <hip/hip_runtime.h>

// ---------------------------------------------------------------------------
// NAFNet-like block, MI355X (gfx950). B=2,C=64,H=W=256,DW=128,FFN=128,GRID=8.
// True inputs + final output: fp32 (per reference). Intermediates: bf16.
// Per-tile GEMMs via mfma_f32_16x16x32_bf16 (pixels on M, out-channels on N).
// ---------------------------------------------------------------------------

typedef __bf16 bf16x8 __attribute__((ext_vector_type(8)));
typedef float f32x4 __attribute__((ext_vector_type(4)));
typedef unsigned short u16x8 __attribute__((ext_vector_type(8)));

__device__ __forceinline__ float b2f(unsigned short u) {
    union { unsigned int i; float f; } x; x.i = ((unsigned int)u) << 16; return x.f;
}
__device__ __forceinline__ unsigned short f2b(float f) {
    union { float f; unsigned int i; } x; x.f = f;
    unsigned int i = x.i;
    return (unsigned short)((i + 0x7FFFu + ((i >> 16) & 1u)) >> 16);  // RNE
}

// ---------------------------------------------------------------------------
// (optional LN) -> modulated 1x1 conv (per-tile GEMM) -> gate / residual.
// Input (NB,64,H,W) fp32 or bf16. Output (NB, GATE?64:NOUT, H, W).
// Grid: (8 pixel-chunks of 128, 64 tiles, NB). Block 256 (4 waves).
// Weights/mod/ln/bias/rowscale are fp32 (true inputs). svec fp32.
// ---------------------------------------------------------------------------
template <int NOUT, bool LN, bool GATE, bool RESID, bool SCALE_S,
          bool IN_F32, bool RES_F32, bool OUT_F32>
__global__ __launch_bounds__(256, 2) void conv_k(
    const void* __restrict__ in_,
    void* __restrict__ out_,
    const float* __restrict__ wb,        // (NOUT,64)
    const float* __restrict__ bias,      // (NOUT)
    const float* __restrict__ mod,       // (NB,NOUT,64,8,8)
    const float* __restrict__ lnw,
    const float* __restrict__ lnb,
    const void* __restrict__ resid_,     // (NB,64,H,W)
    const float* __restrict__ rows,      // (NOUT) beta/gamma
    const float* __restrict__ svec)      // (NB,64)
{
    constexpr int CHOUT = GATE ? 64 : NOUT;
    constexpr int PARTS = 256 / NOUT;   // threads per weight row
    constexpr int CP    = 64 / PARTS;   // columns per thread

    const int tid   = threadIdx.x;
    const int chunk = blockIdx.x;       // 0..7 -> 4 image rows each
    const int uv    = blockIdx.y;       // tile (u,v)
    const int b     = blockIdx.z;
    const int u = uv >> 3, v = uv & 7;
    const int h_base = u * 32 + chunk * 4;
    const int w_base = v * 32;

    __shared__ __align__(16) unsigned short stage[128 * 72]; // [pixel][ch]
    __shared__ __align__(16) unsigned short wlds[NOUT * 72]; // [o][c]
    __shared__ float sbias[NOUT];
    __shared__ float shP[256];
    __shared__ float shsA[256];
    __shared__ float shsB[256];

    // ---- phase 1a: weight partial sums (demod norm over input channels) ----
    const int o_p  = tid & (NOUT - 1);
    const int part = tid / NOUT;
    float wv[CP];
    {
        float ss = 0.f;
#pragma unroll
        for (int j = 0; j < CP; ++j) {
            int c = part * CP + j;
            float wf = wb[o_p * 64 + c];
            float m  = mod[(((b * NOUT + o_p) * 64 + c) << 6) + uv];
            wv[j] = wf * m;
            ss += wv[j] * wv[j];
        }
        shP[o_p * PARTS + part] = ss;
    }

    // ---- phase 1b: input staging loads (coalesced per-channel) ----
    const int p    = tid & 127;
    const int half = tid >> 7;
    const int cbase = half * 32;
    const int pixoff = (h_base + (p >> 5)) * 256 + w_base + (p & 31);
    float v2[32];
    {
        float s1 = 0.f, s2 = 0.f;
#pragma unroll
        for (int j = 0; j < 32; ++j) {
            int idx = ((b * 64 + cbase + j) << 16) + pixoff;
            float xv = IN_F32 ? ((const float*)in_)[idx]
                              : b2f(((const unsigned short*)in_)[idx]);
            v2[j] = xv;
            if constexpr (LN) { s1 += xv; s2 += xv * xv; }
        }
        if constexpr (LN) { shsA[p * 2 + half] = s1; shsB[p * 2 + half] = s2; }
    }

    __syncthreads();

    // ---- phase 2a: weight finalize (normalize, fold rowscale / svec) ----
    {
        float tot = 0.f;
#pragma unroll
        for (int k = 0; k < PARTS; ++k) tot += shP[o_p * PARTS + k];
        float rn = rsqrtf(fmaxf(tot, 1e-30f));
        float rsv = 1.f;
        if constexpr (RESID) { rsv = rows[o_p]; rn *= rsv; }
#pragma unroll
        for (int j = 0; j < CP; ++j) {
            int c = part * CP + j;
            float wf = wv[j] * rn;
            if constexpr (SCALE_S) wf *= svec[b * 64 + c];
            wlds[o_p * 72 + c] = f2b(wf);
        }
        if (part == 0) {
            float bs = bias[o_p];
            if constexpr (RESID) bs *= rsv;
            sbias[o_p] = bs;
        }
    }

    // ---- phase 2b: LN + pack -> LDS pixel-major ----
    {
        float mu = 0.f, rstd = 1.f;
        if constexpr (LN) {
            float S1 = shsA[p * 2] + shsA[p * 2 + 1];
            float S2 = shsB[p * 2] + shsB[p * 2 + 1];
            mu = S1 * (1.f / 64.f);
            float var = S2 * (1.f / 64.f) - mu * mu;
            rstd = rsqrtf(fmaxf(var, 0.f) + 1e-6f);
        }
#pragma unroll
        for (int g = 0; g < 4; ++g) {
            u16x8 pk;
#pragma unroll
            for (int e = 0; e < 8; ++e) {
                int j = g * 8 + e;
                float val = v2[j];
                if constexpr (LN)
                    val = (val - mu) * rstd * lnw[cbase + j] + lnb[cbase + j];
                pk[e] = f2b(val);
            }
            *(u16x8*)&stage[p * 72 + cbase + g * 8] = pk;
        }
    }

    __syncthreads();

    // ---- GEMM: M=128 pixels, N=NOUT, K=64; 16x16x32 bf16 MFMA ----
    const int wave = tid >> 6;
    const int lane = tid & 63;
    const int q = lane >> 4;   // quad
    const int r = lane & 15;

    constexpr int NF = (NOUT == 64) ? 1 : 2;
    int nfi[2];
    if constexpr (NOUT == 64)      { nfi[0] = wave;     nfi[1] = wave; }
    else if constexpr (GATE)       { nfi[0] = wave;     nfi[1] = wave + 4; } // (o,o+64)
    else                           { nfi[0] = 2 * wave; nfi[1] = 2 * wave + 1; }

    bf16x8 bfr[NF][2];
#pragma unroll
    for (int f = 0; f < NF; ++f)
#pragma unroll
        for (int ks = 0; ks < 2; ++ks)
            bfr[f][ks] = *(const bf16x8*)&wlds[(16 * nfi[f] + r) * 72 + ks * 32 + q * 8];

    f32x4 acc[8][NF];
#pragma unroll
    for (int mi = 0; mi < 8; ++mi)
#pragma unroll
        for (int f = 0; f < NF; ++f) acc[mi][f] = (f32x4){0.f, 0.f, 0.f, 0.f};

#pragma unroll
    for (int mi = 0; mi < 8; ++mi) {
        bf16x8 a0 = *(const bf16x8*)&stage[(16 * mi + r) * 72 + q * 8];
        bf16x8 a1 = *(const bf16x8*)&stage[(16 * mi + r) * 72 + 32 + q * 8];
#pragma unroll
        for (int f = 0; f < NF; ++f) {
            acc[mi][f] = __builtin_amdgcn_mfma_f32_16x16x32_bf16(a0, bfr[f][0], acc[mi][f], 0, 0, 0);
            acc[mi][f] = __builtin_amdgcn_mfma_f32_16x16x32_bf16(a1, bfr[f][1], acc[mi][f], 0, 0, 0);
        }
    }

    // ---- epilogue: D reg e holds pixel 16*mi + 4*q + e ----
#pragma unroll
    for (int mi = 0; mi < 8; ++mi) {
        int lp0 = 16 * mi + 4 * q;
        int pix = (h_base + (lp0 >> 5)) * 256 + w_base + (lp0 & 31);
        if constexpr (GATE) {
            int o = 16 * wave + r;
            float ba = sbias[o], bg = sbias[o + 64];
            float g0 = (acc[mi][0][0] + ba) * (acc[mi][1][0] + bg);
            float g1 = (acc[mi][0][1] + ba) * (acc[mi][1][1] + bg);
            float g2 = (acc[mi][0][2] + ba) * (acc[mi][1][2] + bg);
            float g3 = (acc[mi][0][3] + ba) * (acc[mi][1][3] + bg);
            int off = ((b * 64 + o) << 16) + pix;
            *(ushort4*)&((unsigned short*)out_)[off] =
                make_ushort4(f2b(g0), f2b(g1), f2b(g2), f2b(g3));
        } else {
#pragma unroll
            for (int f = 0; f < NF; ++f) {
                int o = 16 * nfi[f] + r;
                float bs = sbias[o];
                float e0 = acc[mi][f][0] + bs, e1 = acc[mi][f][1] + bs;
                float e2 = acc[mi][f][2] + bs, e3 = acc[mi][f][3] + bs;
                int off = ((b * CHOUT + o) << 16) + pix;
                if constexpr (RESID) {
                    if constexpr (RES_F32) {
                        float4 rv = *(const float4*)&((const float*)resid_)[off];
                        e0 += rv.x; e1 += rv.y; e2 += rv.z; e3 += rv.w;
                    } else {
                        ushort4 rv = *(const ushort4*)&((const unsigned short*)resid_)[off];
                        e0 += b2f(rv.x); e1 += b2f(rv.y); e2 += b2f(rv.z); e3 += b2f(rv.w);
                    }
                }
                if constexpr (OUT_F32) {
                    *(float4*)&((float*)out_)[off] = make_float4(e0, e1, e2, e3);
                } else {
                    *(ushort4*)&((unsigned short*)out_)[off] =
                        make_ushort4(f2b(e0), f2b(e1), f2b(e2), f2b(e3));
                }
            }
        }
    }
}

// ---------------------------------------------------------------------------
// Depthwise modulated 3x3 + gate + SCA partial sums. t1/t3 bf16.
// Grid: (64 tiles, 64 out-ch, NB). Block 256; thread = 4 vertical pixels.
// ---------------------------------------------------------------------------
__global__ __launch_bounds__(256, 2) void dw_k(
    const unsigned short* __restrict__ t1,   // (NB,128,H,W) bf16
    unsigned short* __restrict__ t3,         // (NB,64,H,W) bf16
    const float* __restrict__ w2,            // (128,3,3) fp32
    const float* __restrict__ b2,            // (128)
    const float* __restrict__ mod2,          // (NB,128,8,8)
    float* __restrict__ s0)                  // (NB,64) fp32 accum
{
    const int tid = threadIdx.x;
    const int uv = blockIdx.x; const int u = uv >> 3, vv = uv & 7;
    const int oc = blockIdx.y; const int b = blockIdx.z;

    __shared__ unsigned short sh[2][34 * 36];
    __shared__ float wred[4];

    const unsigned short* base_a = t1 + (((size_t)b * 128 + oc) << 16);
    const unsigned short* base_g = t1 + (((size_t)b * 128 + oc + 64) << 16);

    for (int i = tid; i < 2 * 34 * 34; i += 256) {
        int ch = i / 1156; int rem = i - ch * 1156;
        int rr = rem / 34; int cc = rem - rr * 34;
        int gh = u * 32 + rr - 1, gw = vv * 32 + cc - 1;
        unsigned short uval = 0;
        if (gh >= 0 && gh < 256 && gw >= 0 && gw < 256)
            uval = (ch ? base_g : base_a)[gh * 256 + gw];
        sh[ch][rr * 36 + cc] = uval;
    }

    float wa[9], wg[9];
    float ssa = 0.f, ssg = 0.f;
#pragma unroll
    for (int k = 0; k < 9; ++k) {
        wa[k] = w2[oc * 9 + k];        ssa += wa[k] * wa[k];
        wg[k] = w2[(oc + 64) * 9 + k]; ssg += wg[k] * wg[k];
    }
    float ma = mod2[(b * 128 + oc) * 64 + uv];
    float mg = mod2[(b * 128 + oc + 64) * 64 + uv];
    float rna = ma * rsqrtf(fmaxf(ma * ma * ssa, 1e-30f));
    float rng = mg * rsqrtf(fmaxf(mg * mg * ssg, 1e-30f));
#pragma unroll
    for (int k = 0; k < 9; ++k) { wa[k] *= rna; wg[k] *= rng; }
    float ba = b2[oc], bg = b2[oc + 64];

    __syncthreads();

    const int col  = tid & 31;
    const int row4 = (tid >> 5) * 4;

    float win_a[6][3], win_g[6][3];
#pragma unroll
    for (int dr = 0; dr < 6; ++dr)
#pragma unroll
        for (int dc = 0; dc < 3; ++dc) {
            win_a[dr][dc] = b2f(sh[0][(row4 + dr) * 36 + col + dc]);
            win_g[dr][dc] = b2f(sh[1][(row4 + dr) * 36 + col + dc]);
        }

    unsigned short* outb = t3 + (((size_t)b * 64 + oc) << 16);
    float psum = 0.f;
#pragma unroll
    for (int i = 0; i < 4; ++i) {
        float a = 0.f, g = 0.f;
#pragma unroll
        for (int kh = 0; kh < 3; ++kh)
#pragma unroll
            for (int kw = 0; kw < 3; ++kw) {
                a += wa[kh * 3 + kw] * win_a[i + kh][kw];
                g += wg[kh * 3 + kw] * win_g[i + kh][kw];
            }
        float val = (a + ba) * (g + bg);
        psum += val;
        outb[(u * 32 + row4 + i) * 256 + vv * 32 + col] = f2b(val);
    }

    for (int off = 32; off > 0; off >>= 1) psum += __shfl_down(psum, off, 64);
    if ((tid & 63) == 0) wred[tid >> 6] = psum;
    __syncthreads();
    if (tid == 0) atomicAdd(&s0[b * 64 + oc], wred[0] + wred[1] + wred[2] + wred[3]);
}

// ---------------------------------------------------------------------------
// SCA: sfin[b,o] = sum_c sca_w[o,c] * (s0[b,c]/65536) + sca_b[o]
// ---------------------------------------------------------------------------
__global__ void sca_k(const float* __restrict__ s0,
                      const float* __restrict__ scaw,
                      const float* __restrict__ scab,
                      float* __restrict__ sfin)
{
    int t = threadIdx.x;
    int b = t >> 6, o = t & 63;
    float acc = 0.f;
#pragma unroll 8
    for (int c = 0; c < 64; ++c)
        acc += scaw[o * 64 + c] * s0[b * 64 + c];
    sfin[b * 64 + o] = acc * (1.f / 65536.f) + scab[o];
}

// ---------------------------------------------------------------------------
extern "C" void kernel_launch(void* const* d_in, const int* in_sizes, int n_in,
                              void* d_out, int out_size, void* d_ws, size_t ws_size,
                              hipStream_t stream) {
    (void)in_sizes; (void)n_in; (void)out_size;
    const float* x    = (const float*)d_in[0];
    const float* w1   = (const float*)d_in[1];
    const float* b1   = (const float*)d_in[2];
    const float* w2   = (const float*)d_in[3];
    const float* b2   = (const float*)d_in[4];
    const float* w3   = (const float*)d_in[5];
    const float* b3   = (const float*)d_in[6];
    const float* scaw = (const float*)d_in[7];
    const float* scab = (const float*)d_in[8];
    const float* w4   = (const float*)d_in[9];
    const float* b4   = (const float*)d_in[10];
    const float* w5   = (const float*)d_in[11];
    const float* b5   = (const float*)d_in[12];
    const float* n1w  = (const float*)d_in[13];
    const float* n1b  = (const float*)d_in[14];
    const float* n2w  = (const float*)d_in[15];
    const float* n2b  = (const float*)d_in[16];
    const float* beta = (const float*)d_in[17];
    const float* gam  = (const float*)d_in[18];
    const float* mod1 = (const float*)d_in[19];
    const float* mod2 = (const float*)d_in[20];
    const float* mod3 = (const float*)d_in[21];
    const float* mod4 = (const float*)d_in[22];
    const float* mod5 = (const float*)d_in[23];

    char* ws = (char*)d_ws;
    float* outf = (float*)d_out;

    const size_t IMGel = (size_t)64 * 65536;          // elements per 64ch image
    const size_t T1B   = (size_t)128 * 65536 * 2;     // t1 bytes per batch (bf16)

    const size_t needA = 2 * T1B + 2048;              // ~33.6 MB
    const bool planA = ws_size >= needA;

    dim3 blk(256);

    if (planA) {
        unsigned short* t1 = (unsigned short*)ws;                 // 33.55 MB
        unsigned short* y1 = (unsigned short*)ws;                 // 16.78 MB (reuse)
        unsigned short* t4 = (unsigned short*)(ws + 2 * IMGel * 2);
        unsigned short* t3 = (unsigned short*)d_out;              // scratch in d_out
        char* statb = ws + 2 * T1B;
        float* s0   = (float*)statb;
        float* sfin = (float*)(statb + 512);

        hipMemsetAsync(s0, 0, 512, stream);
        dim3 gconv(8, 64, 2), gdw(64, 64, 2);

        conv_k<128, true, false, false, false, true, false, false><<<gconv, blk, 0, stream>>>(
            x, t1, w1, b1, mod1, n1w, n1b, nullptr, nullptr, nullptr);
        dw_k<<<gdw, blk, 0, stream>>>(t1, t3, w2, b2, mod2, s0);
        sca_k<<<1, 128, 0, stream>>>(s0, scaw, scab, sfin);
        conv_k<64, false, false, true, true, false, true, false><<<gconv, blk, 0, stream>>>(
            t3, y1, w3, b3, mod3, nullptr, nullptr, x, beta, sfin);
        conv_k<128, true, true, false, false, false, false, false><<<gconv, blk, 0, stream>>>(
            y1, t4, w4, b4, mod4, n2w, n2b, nullptr, nullptr, nullptr);
        conv_k<64, false, false, true, false, false, false, true><<<gconv, blk, 0, stream>>>(
            t4, outf, w5, b5, mod5, nullptr, nullptr, y1, gam, nullptr);
    } else {
        // Plan B: per-batch sequential; needs ~16.8 MB ws. t3 staged inside the
        // batch's d_out region (dead before conv5's fp32 overwrite).
        for (int bb = 0; bb < 2; ++bb) {
            const float* x_b    = x    + (size_t)bb * IMGel;
            float*       out_b  = outf + (size_t)bb * IMGel;
            const float* mod1_b = mod1 + (size_t)bb * 128 * 64 * 64;
            const float* mod2_b = mod2 + (size_t)bb * 128 * 64;
            const float* mod3_b = mod3 + (size_t)bb * 64 * 64 * 64;
            const float* mod4_b = mod4 + (size_t)bb * 128 * 64 * 64;
            const float* mod5_b = mod5 + (size_t)bb * 64 * 64 * 64;

            unsigned short* t1 = (unsigned short*)ws;             // 16.78 MB
            unsigned short* y1 = (unsigned short*)ws;             // 8.39 MB (reuse)
            unsigned short* t4 = (unsigned short*)(ws + IMGel * 2);
            unsigned short* t3 = (unsigned short*)out_b;          // 8.39 MB in d_out
            char* statb = ws + T1B;
            float* s0   = (float*)statb;
            float* sfin = (float*)(statb + 256);

            hipMemsetAsync(s0, 0, 256, stream);
            dim3 gconv(8, 64, 1), gdw(64, 64, 1);

            conv_k<128, true, false, false, false, true, false, false><<<gconv, blk, 0, stream>>>(
                x_b, t1, w1, b1, mod1_b, n1w, n1b, nullptr, nullptr, nullptr);
            dw_k<<<gdw, blk, 0, stream>>>(t1, t3, w2, b2, mod2_b, s0);
            sca_k<<<1, 64, 0, stream>>>(s0, scaw, scab, sfin);
            conv_k<64, false, false, true, true, false, true, false><<<gconv, blk, 0, stream>>>(
                t3, y1, w3, b3, mod3_b, nullptr, nullptr, x_b, beta, sfin);
            conv_k<128, true, true, false, false, false, false, false><<<gconv, blk, 0, stream>>>(
                y1, t4, w4, b4, mod4_b, n2w, n2b, nullptr, nullptr, nullptr);
            conv_k<64, false, false, true, false, false, false, true><<<gconv, blk, 0, stream>>>(
                t4, out_b, w5, b5, mod5_b, nullptr, nullptr, y1, gam, nullptr);
        }
    }
}

// Round 5
// 240.934 us; speedup vs baseline: 1.4005x; 1.4005x over previous
//
#include <hip/hip_runtime.h>

// ---------------------------------------------------------------------------
// NAFNet-like block, MI355X (gfx950). B=2,C=64,H=W=256,DW=128,FFN=128,GRID=8.
// fp32 true inputs + fp32 output; bf16 intermediates; MFMA 16x16x32 bf16.
// R4: (1) dw_k rewritten: 8px/thread, direct vector loads, shfl halo.
//     (2) prep_k precomputes demodulated bf16 weight tables (coalesced mod
//         reads) for conv1/3/4 into d_out tail; conv5 keeps inline weights.
//     (3) SCA scale folded into conv3 INPUT staging (prep data-independent).
// ---------------------------------------------------------------------------

typedef __bf16 bf16x8 __attribute__((ext_vector_type(8)));
typedef float f32x4 __attribute__((ext_vector_type(4)));
typedef unsigned short u16x8 __attribute__((ext_vector_type(8)));

__device__ __forceinline__ float b2f(unsigned short u) {
    union { unsigned int i; float f; } x; x.i = ((unsigned int)u) << 16; return x.f;
}
__device__ __forceinline__ unsigned short f2b(float f) {
    union { float f; unsigned int i; } x; x.f = f;
    unsigned int i = x.i;
    return (unsigned short)((i + 0x7FFFu + ((i >> 16) & 1u)) >> 16);  // RNE
}

// ---------------------------------------------------------------------------
// prep_k: demodulated weight tables for conv1/3/4.
// pw layout: [b][uv][o][c] bf16 (c contiguous). Block = one (conv,b,o) row.
// Grid 640 = 256(conv1) + 128(conv3) + 256(conv4).
// ---------------------------------------------------------------------------
__global__ __launch_bounds__(256) void prep_k(
    const float* __restrict__ w1, const float* __restrict__ mod1,
    const float* __restrict__ w3, const float* __restrict__ mod3,
    const float* __restrict__ beta,
    const float* __restrict__ w4, const float* __restrict__ mod4,
    unsigned short* __restrict__ pw1, unsigned short* __restrict__ pw3,
    unsigned short* __restrict__ pw4)
{
    const int tid = threadIdx.x;
    int blk = blockIdx.x;
    const float* w; const float* mod; const float* rows = nullptr;
    unsigned short* out; int NOUT; int rem;
    if (blk < 256)      { w = w1; mod = mod1; out = pw1; NOUT = 128; rem = blk; }
    else if (blk < 384) { w = w3; mod = mod3; out = pw3; NOUT = 64; rem = blk - 256; rows = beta; }
    else                { w = w4; mod = mod4; out = pw4; NOUT = 128; rem = blk - 384; }
    const int b = rem / NOUT, o = rem % NOUT;

    __shared__ float mlds[64 * 68];   // [c][uv], pad 68 (16B-aligned rows)
    __shared__ float wlsh[64];
    __shared__ float red[4 * 64];
    __shared__ float rs[64];

    const float* mbase = mod + ((size_t)(b * NOUT + o) * 64) * 64;  // [c][uv]
#pragma unroll
    for (int k = 0; k < 4; ++k) {
        int l = tid + k * 256;            // float4 index
        float4 vv = ((const float4*)mbase)[l];
        int c = l >> 4, q = l & 15;
        *(float4*)&mlds[c * 68 + q * 4] = vv;
    }
    if (tid < 64) wlsh[tid] = w[o * 64 + tid];
    __syncthreads();

    {
        int uv = tid & 63, part = tid >> 6;
        float ss = 0.f;
#pragma unroll
        for (int j = 0; j < 16; ++j) {
            int c = part * 16 + j;
            float t = wlsh[c] * mlds[c * 68 + uv];
            ss += t * t;
        }
        red[part * 64 + uv] = ss;
    }
    __syncthreads();
    if (tid < 64) {
        float tot = red[tid] + red[64 + tid] + red[128 + tid] + red[192 + tid];
        float rv = rows ? rows[o] : 1.f;
        rs[tid] = rsqrtf(fmaxf(tot, 1e-30f)) * rv;
    }
    __syncthreads();

    {
        int uvw = tid >> 2, cp = tid & 3;
        float r = rs[uvw];
        size_t obase = ((size_t)(b * 64 + uvw) * NOUT + o) * 64;
#pragma unroll
        for (int g = 0; g < 2; ++g) {
            u16x8 pk;
#pragma unroll
            for (int e = 0; e < 8; ++e) {
                int c = cp * 16 + g * 8 + e;
                pk[e] = f2b(wlsh[c] * mlds[c * 68 + uvw] * r);
            }
            *(u16x8*)&out[obase + cp * 16 + g * 8] = pk;
        }
    }
}

// ---------------------------------------------------------------------------
// conv_k: (optional LN / input-scale) -> 1x1 modulated conv GEMM -> gate /
// residual. PREPPED: weights from pw table; else inline demod (conv5).
// Grid: (8 chunks of 128px, 64 tiles, NB). Block 256 (4 waves).
// ---------------------------------------------------------------------------
template <int NOUT, bool LN, bool GATE, bool RESID, bool SCALE_IN,
          bool IN_F32, bool RES_F32, bool OUT_F32, bool PREPPED>
__global__ __launch_bounds__(256, 2) void conv_k(
    const void* __restrict__ in_,
    void* __restrict__ out_,
    const unsigned short* __restrict__ pw,   // prepped table (PREPPED)
    const float* __restrict__ wb,            // inline path
    const float* __restrict__ mod,           // inline path
    const float* __restrict__ bias,
    const float* __restrict__ lnw,
    const float* __restrict__ lnb,
    const void* __restrict__ resid_,
    const float* __restrict__ rows,          // beta/gamma
    const float* __restrict__ svec,          // (2,64) for SCALE_IN
    int bbase)
{
    constexpr int CHOUT = GATE ? 64 : NOUT;
    constexpr int PARTS = 256 / NOUT;
    constexpr int CP    = 64 / PARTS;

    const int tid   = threadIdx.x;
    const int chunk = blockIdx.x;
    const int uv    = blockIdx.y;
    const int z     = blockIdx.z;        // local batch (pointer-relative)
    const int bfull = z + bbase;         // absolute batch (pw/mod/svec)
    const int u = uv >> 3, v = uv & 7;
    const int h_base = u * 32 + chunk * 4;
    const int w_base = v * 32;

    __shared__ __align__(16) unsigned short stage[128 * 72];
    __shared__ __align__(16) unsigned short wlds[NOUT * 72];
    __shared__ float sbias[NOUT];
    __shared__ float shP[PREPPED ? 1 : 256];
    __shared__ float shsA[LN ? 256 : 1];
    __shared__ float shsB[LN ? 256 : 1];

    const int o_p  = tid & (NOUT - 1);
    const int part = tid / NOUT;
    float wv[PREPPED ? 1 : CP];

    // ---- phase 1: weights ----
    if constexpr (PREPPED) {
        constexpr int CH = NOUT / 32;    // u16x8 chunks per thread
        const unsigned short* pwb = pw + ((size_t)(bfull * 64 + uv) * NOUT) * 64;
#pragma unroll
        for (int k = 0; k < CH; ++k) {
            int ci = tid + k * 256;
            *(u16x8*)&wlds[(ci >> 3) * 72 + (ci & 7) * 8] = *(const u16x8*)&pwb[ci * 8];
        }
        if (tid < NOUT) {
            float bs = bias[tid];
            if constexpr (RESID) bs *= rows[tid];
            sbias[tid] = bs;
        }
    } else {
        float ss = 0.f;
#pragma unroll
        for (int j = 0; j < CP; ++j) {
            int c = part * CP + j;
            float wf = wb[o_p * 64 + c];
            float m  = mod[(((bfull * NOUT + o_p) * 64 + c) << 6) + uv];
            wv[j] = wf * m;
            ss += wv[j] * wv[j];
        }
        shP[o_p * PARTS + part] = ss;
    }

    // ---- phase 1b: input staging loads (coalesced per-channel) ----
    const int p    = tid & 127;
    const int half = tid >> 7;
    const int cbase = half * 32;
    const int pixoff = (h_base + (p >> 5)) * 256 + w_base + (p & 31);
    float v2[32];
    {
        float s1 = 0.f, s2 = 0.f;
#pragma unroll
        for (int j = 0; j < 32; ++j) {
            int idx = ((z * 64 + cbase + j) << 16) + pixoff;
            float xv = IN_F32 ? ((const float*)in_)[idx]
                              : b2f(((const unsigned short*)in_)[idx]);
            v2[j] = xv;
            if constexpr (LN) { s1 += xv; s2 += xv * xv; }
        }
        if constexpr (LN) { shsA[p * 2 + half] = s1; shsB[p * 2 + half] = s2; }
    }

    // !LN: pack immediately (no cross-thread dependency)
    if constexpr (!LN) {
#pragma unroll
        for (int g = 0; g < 4; ++g) {
            u16x8 pk;
#pragma unroll
            for (int e = 0; e < 8; ++e) {
                int j = g * 8 + e;
                float val = v2[j];
                if constexpr (SCALE_IN) val *= svec[bfull * 64 + cbase + j];
                pk[e] = f2b(val);
            }
            *(u16x8*)&stage[p * 72 + cbase + g * 8] = pk;
        }
    }

    if constexpr (LN || !PREPPED) __syncthreads();

    if constexpr (!PREPPED) {   // inline weight finalize
        float tot = 0.f;
#pragma unroll
        for (int k = 0; k < PARTS; ++k) tot += shP[o_p * PARTS + k];
        float rn = rsqrtf(fmaxf(tot, 1e-30f));
        float rsv = 1.f;
        if constexpr (RESID) { rsv = rows[o_p]; rn *= rsv; }
#pragma unroll
        for (int j = 0; j < CP; ++j)
            wlds[o_p * 72 + part * CP + j] = f2b(wv[j] * rn);
        if (part == 0) {
            float bs = bias[o_p];
            if constexpr (RESID) bs *= rsv;
            sbias[o_p] = bs;
        }
    }

    if constexpr (LN) {
        float S1 = shsA[p * 2] + shsA[p * 2 + 1];
        float S2 = shsB[p * 2] + shsB[p * 2 + 1];
        float mu = S1 * (1.f / 64.f);
        float var = S2 * (1.f / 64.f) - mu * mu;
        float rstd = rsqrtf(fmaxf(var, 0.f) + 1e-6f);
#pragma unroll
        for (int g = 0; g < 4; ++g) {
            u16x8 pk;
#pragma unroll
            for (int e = 0; e < 8; ++e) {
                int j = g * 8 + e;
                float val = (v2[j] - mu) * rstd * lnw[cbase + j] + lnb[cbase + j];
                pk[e] = f2b(val);
            }
            *(u16x8*)&stage[p * 72 + cbase + g * 8] = pk;
        }
    }

    __syncthreads();

    // ---- GEMM: M=128 px, N=NOUT, K=64; 16x16x32 bf16 MFMA ----
    const int wave = tid >> 6;
    const int lane = tid & 63;
    const int q = lane >> 4;
    const int r = lane & 15;

    constexpr int NF = (NOUT == 64) ? 1 : 2;
    int nfi[2];
    if constexpr (NOUT == 64)      { nfi[0] = wave;     nfi[1] = wave; }
    else if constexpr (GATE)       { nfi[0] = wave;     nfi[1] = wave + 4; }
    else                           { nfi[0] = 2 * wave; nfi[1] = 2 * wave + 1; }

    bf16x8 bfr[NF][2];
#pragma unroll
    for (int f = 0; f < NF; ++f)
#pragma unroll
        for (int ks = 0; ks < 2; ++ks)
            bfr[f][ks] = *(const bf16x8*)&wlds[(16 * nfi[f] + r) * 72 + ks * 32 + q * 8];

    f32x4 acc[8][NF];
#pragma unroll
    for (int mi = 0; mi < 8; ++mi)
#pragma unroll
        for (int f = 0; f < NF; ++f) acc[mi][f] = (f32x4){0.f, 0.f, 0.f, 0.f};

#pragma unroll
    for (int mi = 0; mi < 8; ++mi) {
        bf16x8 a0 = *(const bf16x8*)&stage[(16 * mi + r) * 72 + q * 8];
        bf16x8 a1 = *(const bf16x8*)&stage[(16 * mi + r) * 72 + 32 + q * 8];
#pragma unroll
        for (int f = 0; f < NF; ++f) {
            acc[mi][f] = __builtin_amdgcn_mfma_f32_16x16x32_bf16(a0, bfr[f][0], acc[mi][f], 0, 0, 0);
            acc[mi][f] = __builtin_amdgcn_mfma_f32_16x16x32_bf16(a1, bfr[f][1], acc[mi][f], 0, 0, 0);
        }
    }

    // ---- epilogue ----
#pragma unroll
    for (int mi = 0; mi < 8; ++mi) {
        int lp0 = 16 * mi + 4 * q;
        int pix = (h_base + (lp0 >> 5)) * 256 + w_base + (lp0 & 31);
        if constexpr (GATE) {
            int o = 16 * wave + r;
            float ba = sbias[o], bg = sbias[o + 64];
            float g0 = (acc[mi][0][0] + ba) * (acc[mi][1][0] + bg);
            float g1 = (acc[mi][0][1] + ba) * (acc[mi][1][1] + bg);
            float g2 = (acc[mi][0][2] + ba) * (acc[mi][1][2] + bg);
            float g3 = (acc[mi][0][3] + ba) * (acc[mi][1][3] + bg);
            int off = ((z * 64 + o) << 16) + pix;
            *(ushort4*)&((unsigned short*)out_)[off] =
                make_ushort4(f2b(g0), f2b(g1), f2b(g2), f2b(g3));
        } else {
#pragma unroll
            for (int f = 0; f < NF; ++f) {
                int o = 16 * nfi[f] + r;
                float bs = sbias[o];
                float e0 = acc[mi][f][0] + bs, e1 = acc[mi][f][1] + bs;
                float e2 = acc[mi][f][2] + bs, e3 = acc[mi][f][3] + bs;
                int off = ((z * CHOUT + o) << 16) + pix;
                if constexpr (RESID) {
                    if constexpr (RES_F32) {
                        float4 rv = *(const float4*)&((const float*)resid_)[off];
                        e0 += rv.x; e1 += rv.y; e2 += rv.z; e3 += rv.w;
                    } else {
                        ushort4 rv = *(const ushort4*)&((const unsigned short*)resid_)[off];
                        e0 += b2f(rv.x); e1 += b2f(rv.y); e2 += b2f(rv.z); e3 += b2f(rv.w);
                    }
                }
                if constexpr (OUT_F32) {
                    *(float4*)&((float*)out_)[off] = make_float4(e0, e1, e2, e3);
                } else {
                    *(ushort4*)&((unsigned short*)out_)[off] =
                        make_ushort4(f2b(e0), f2b(e1), f2b(e2), f2b(e3));
                }
            }
        }
    }
}

// ---------------------------------------------------------------------------
// dw_k: depthwise 3x3 modulated + gate + SCA partials. 8 px/thread, direct
// global vector loads (no LDS tile), halo via shuffles (image-border zeros).
// Grid: (32 row-bands of 8, 64 oc, NB). Block 256.
// ---------------------------------------------------------------------------
__global__ __launch_bounds__(256, 4) void dw_k(
    const unsigned short* __restrict__ t1,   // (NB,128,H,W) bf16
    unsigned short* __restrict__ t3,         // (NB,64,H,W) bf16
    const float* __restrict__ w2,            // (128,3,3)
    const float* __restrict__ b2,            // (128)
    const float* __restrict__ mod2,          // (2,128,8,8)
    float* __restrict__ s0,                  // (2,64)
    int bbase)
{
    const int tid  = threadIdx.x;
    const int band = blockIdx.x;             // 8 rows
    const int oc   = blockIdx.y;
    const int z    = blockIdx.z;
    const int bfull = z + bbase;
    const int u = band >> 2;                 // tile row

    __shared__ float wl[2][8][9];
    __shared__ float wred[4];

    // per-(v,half) demodulated weights
    if (tid < 16) {
        int halfc = tid >> 3, vv = tid & 7;
        const float* wrow = w2 + (oc + halfc * 64) * 9;
        float wloc[9], ssum = 0.f;
#pragma unroll
        for (int k = 0; k < 9; ++k) { wloc[k] = wrow[k]; ssum += wloc[k] * wloc[k]; }
        float m = mod2[(bfull * 128 + oc + halfc * 64) * 64 + u * 8 + vv];
        float rn = m * rsqrtf(fmaxf(m * m * ssum, 1e-30f));
#pragma unroll
        for (int k = 0; k < 9; ++k) wl[halfc][vv][k] = wloc[k] * rn;
    }
    __syncthreads();

    const int strip = tid & 31;              // 8-px strip
    const int row   = band * 8 + (tid >> 5);
    const int v     = strip >> 2;

    float wa[9], wg[9];
#pragma unroll
    for (int k = 0; k < 9; ++k) { wa[k] = wl[0][v][k]; wg[k] = wl[1][v][k]; }
    const float ba = b2[oc], bg = b2[oc + 64];

    const unsigned short* pa = t1 + (((size_t)z * 128 + oc) << 16);
    const unsigned short* pg = pa + ((size_t)64 << 16);

    float fa[3][8], fg[3][8], la[3], ra[3], lg[3], rg[3];
#pragma unroll
    for (int dr = 0; dr < 3; ++dr) {
        int rr = row - 1 + dr;
        if (rr >= 0 && rr < 256) {
            u16x8 va = *(const u16x8*)&pa[rr * 256 + strip * 8];
            u16x8 vg = *(const u16x8*)&pg[rr * 256 + strip * 8];
#pragma unroll
            for (int e = 0; e < 8; ++e) { fa[dr][e] = b2f(va[e]); fg[dr][e] = b2f(vg[e]); }
        } else {
#pragma unroll
            for (int e = 0; e < 8; ++e) { fa[dr][e] = 0.f; fg[dr][e] = 0.f; }
        }
        float t;
        t = __shfl_up(fa[dr][7], 1);   la[dr] = (strip == 0)  ? 0.f : t;
        t = __shfl_up(fg[dr][7], 1);   lg[dr] = (strip == 0)  ? 0.f : t;
        t = __shfl_down(fa[dr][0], 1); ra[dr] = (strip == 31) ? 0.f : t;
        t = __shfl_down(fg[dr][0], 1); rg[dr] = (strip == 31) ? 0.f : t;
    }

    float psum = 0.f;
    u16x8 pk;
#pragma unroll
    for (int j = 0; j < 8; ++j) {
        float a = 0.f, g = 0.f;
#pragma unroll
        for (int dr = 0; dr < 3; ++dr) {
            float m1a = (j == 0) ? la[dr] : fa[dr][j - 1];
            float p1a = (j == 7) ? ra[dr] : fa[dr][j + 1];
            float m1g = (j == 0) ? lg[dr] : fg[dr][j - 1];
            float p1g = (j == 7) ? rg[dr] : fg[dr][j + 1];
            a += wa[dr * 3] * m1a + wa[dr * 3 + 1] * fa[dr][j] + wa[dr * 3 + 2] * p1a;
            g += wg[dr * 3] * m1g + wg[dr * 3 + 1] * fg[dr][j] + wg[dr * 3 + 2] * p1g;
        }
        float val = (a + ba) * (g + bg);
        psum += val;
        pk[j] = f2b(val);
    }
    *(u16x8*)&t3[(((size_t)z * 64 + oc) << 16) + row * 256 + strip * 8] = pk;

    for (int off = 32; off > 0; off >>= 1) psum += __shfl_down(psum, off, 64);
    if ((tid & 63) == 0) wred[tid >> 6] = psum;
    __syncthreads();
    if (tid == 0)
        atomicAdd(&s0[bfull * 64 + oc], wred[0] + wred[1] + wred[2] + wred[3]);
}

// ---------------------------------------------------------------------------
__global__ void sca_k(const float* __restrict__ s0,
                      const float* __restrict__ scaw,
                      const float* __restrict__ scab,
                      float* __restrict__ sfin)
{
    int t = threadIdx.x;
    int b = t >> 6, o = t & 63;
    float acc = 0.f;
#pragma unroll 8
    for (int c = 0; c < 64; ++c)
        acc += scaw[o * 64 + c] * s0[b * 64 + c];
    sfin[b * 64 + o] = acc * (1.f / 65536.f) + scab[o];
}

// ---------------------------------------------------------------------------
extern "C" void kernel_launch(void* const* d_in, const int* in_sizes, int n_in,
                              void* d_out, int out_size, void* d_ws, size_t ws_size,
                              hipStream_t stream) {
    (void)in_sizes; (void)n_in; (void)out_size;
    const float* x    = (const float*)d_in[0];
    const float* w1   = (const float*)d_in[1];
    const float* b1   = (const float*)d_in[2];
    const float* w2   = (const float*)d_in[3];
    const float* b2   = (const float*)d_in[4];
    const float* w3   = (const float*)d_in[5];
    const float* b3   = (const float*)d_in[6];
    const float* scaw = (const float*)d_in[7];
    const float* scab = (const float*)d_in[8];
    const float* w4   = (const float*)d_in[9];
    const float* b4   = (const float*)d_in[10];
    const float* w5   = (const float*)d_in[11];
    const float* b5   = (const float*)d_in[12];
    const float* n1w  = (const float*)d_in[13];
    const float* n1b  = (const float*)d_in[14];
    const float* n2w  = (const float*)d_in[15];
    const float* n2b  = (const float*)d_in[16];
    const float* beta = (const float*)d_in[17];
    const float* gam  = (const float*)d_in[18];
    const float* mod1 = (const float*)d_in[19];
    const float* mod2 = (const float*)d_in[20];
    const float* mod3 = (const float*)d_in[21];
    const float* mod4 = (const float*)d_in[22];
    const float* mod5 = (const float*)d_in[23];

    char* ws = (char*)d_ws;
    float* outf = (float*)d_out;

    const size_t IMGel = (size_t)64 * 65536;       // elems per 64ch image
    const size_t T1B   = (size_t)128 * 65536 * 2;  // t1 bytes per batch (bf16)

    // prep tables live in the TAIL of d_out (33.55 MB): dead until conv5,
    // and conv5 uses inline weights so no read/write race.
    const size_t OUTBYTES = 2 * IMGel * 4;               // 33,554,432
    const size_t PWB1 = 2097152, PWB3 = 1048576, PWB4 = 2097152;
    char* pwbase = (char*)d_out + OUTBYTES - (PWB1 + PWB3 + PWB4);
    unsigned short* pw1 = (unsigned short*)pwbase;
    unsigned short* pw3 = (unsigned short*)(pwbase + PWB1);
    unsigned short* pw4 = (unsigned short*)(pwbase + PWB1 + PWB3);

    const size_t needA = 2 * T1B + 2048;
    const bool planA = ws_size >= needA;

    dim3 blk(256);

    if (planA) {
        unsigned short* t1 = (unsigned short*)ws;
        unsigned short* y1 = (unsigned short*)ws;
        unsigned short* t4 = (unsigned short*)(ws + 2 * IMGel * 2);
        unsigned short* t3 = (unsigned short*)d_out;          // [0, 16.78MB)
        char* statb = ws + 2 * T1B;
        float* s0   = (float*)statb;
        float* sfin = (float*)(statb + 512);

        hipMemsetAsync(s0, 0, 512, stream);
        prep_k<<<640, blk, 0, stream>>>(w1, mod1, w3, mod3, beta, w4, mod4,
                                        pw1, pw3, pw4);
        dim3 gconv(8, 64, 2), gdw(32, 64, 2);

        conv_k<128, true, false, false, false, true, false, false, true>
            <<<gconv, blk, 0, stream>>>(x, t1, pw1, nullptr, nullptr, b1,
                                        n1w, n1b, nullptr, nullptr, nullptr, 0);
        dw_k<<<gdw, blk, 0, stream>>>(t1, t3, w2, b2, mod2, s0, 0);
        sca_k<<<1, 128, 0, stream>>>(s0, scaw, scab, sfin);
        conv_k<64, false, false, true, true, false, true, false, true>
            <<<gconv, blk, 0, stream>>>(t3, y1, pw3, nullptr, nullptr, b3,
                                        nullptr, nullptr, x, beta, sfin, 0);
        conv_k<128, true, true, false, false, false, false, false, true>
            <<<gconv, blk, 0, stream>>>(y1, t4, pw4, nullptr, nullptr, b4,
                                        n2w, n2b, nullptr, nullptr, nullptr, 0);
        conv_k<64, false, false, true, false, false, false, true, false>
            <<<gconv, blk, 0, stream>>>(t4, outf, nullptr, w5, mod5, b5,
                                        nullptr, nullptr, y1, gam, nullptr, 0);
    } else {
        // Plan B: per-batch sequential (~16.8 MB ws). t3_b in the batch's own
        // d_out region (first 8.39 MB), overwritten later by conv5.
        char* statb = ws + T1B;
        float* s0   = (float*)statb;
        float* sfin = (float*)(statb + 512);
        hipMemsetAsync(s0, 0, 512, stream);
        prep_k<<<640, blk, 0, stream>>>(w1, mod1, w3, mod3, beta, w4, mod4,
                                        pw1, pw3, pw4);

        for (int bb = 0; bb < 2; ++bb) {
            const float* x_b   = x    + (size_t)bb * IMGel;
            float*       out_b = outf + (size_t)bb * IMGel;
            const float* mod5_b = mod5;  // conv5 inline uses bfull via bbase

            unsigned short* t1 = (unsigned short*)ws;
            unsigned short* y1 = (unsigned short*)ws;
            unsigned short* t4 = (unsigned short*)(ws + IMGel * 2);
            unsigned short* t3 = (unsigned short*)out_b;

            dim3 gconv(8, 64, 1), gdw(32, 64, 1);

            conv_k<128, true, false, false, false, true, false, false, true>
                <<<gconv, blk, 0, stream>>>(x_b, t1, pw1, nullptr, nullptr, b1,
                                            n1w, n1b, nullptr, nullptr, nullptr, bb);
            dw_k<<<gdw, blk, 0, stream>>>(t1, t3, w2, b2, mod2, s0, bb);
            sca_k<<<1, 128, 0, stream>>>(s0, scaw, scab, sfin);
            conv_k<64, false, false, true, true, false, true, false, true>
                <<<gconv, blk, 0, stream>>>(t3, y1, pw3, nullptr, nullptr, b3,
                                            nullptr, nullptr, x_b, beta, sfin, bb);
            conv_k<128, true, true, false, false, false, false, false, true>
                <<<gconv, blk, 0, stream>>>(y1, t4, pw4, nullptr, nullptr, b4,
                                            n2w, n2b, nullptr, nullptr, nullptr, bb);
            conv_k<64, false, false, true, false, false, false, true, false>
                <<<gconv, blk, 0, stream>>>(t4, out_b, nullptr, w5, mod5_b, b5,
                                            nullptr, nullptr, y1, gam, nullptr, bb);
        }
    }
}

// Round 6
// 225.719 us; speedup vs baseline: 1.4949x; 1.0674x over previous
//
#include <hip/hip_runtime.h>
#include <hip/hip_bf16.h>

// ---------------------------------------------------------------------------
// NAFNet-like block, MI355X (gfx950). B=2,C=64,H=W=256,DW=128,FFN=128,GRID=8.
// fp32 true inputs + fp32 output; bf16 intermediates; MFMA 16x16x32 bf16.
// R5: (1) conv_k staging vectorized: 8x float4/ushort4 loads (was 32 scalar),
//         LN via intra-wave shfl_xor (no LDS round-trip), packed bf16 cvt.
//     (2) conv5 weights prepped too (pw5 in d_ws; ws measured ~268MB).
// ---------------------------------------------------------------------------

typedef __bf16 bf16x8 __attribute__((ext_vector_type(8)));
typedef float f32x4 __attribute__((ext_vector_type(4)));
typedef unsigned short u16x8 __attribute__((ext_vector_type(8)));

__device__ __forceinline__ float b2f(unsigned short u) {
    union { unsigned int i; float f; } x; x.i = ((unsigned int)u) << 16; return x.f;
}
__device__ __forceinline__ unsigned short f2b(float f) {
    union { float f; unsigned int i; } x; x.f = f;
    unsigned int i = x.i;
    return (unsigned short)((i + 0x7FFFu + ((i >> 16) & 1u)) >> 16);  // RNE
}
__device__ __forceinline__ unsigned int pk2(float a, float b) {
    __hip_bfloat162 h = __float22bfloat162_rn(float2{a, b});  // v_cvt_pk_bf16_f32
    union { __hip_bfloat162 h; unsigned int u; } cv; cv.h = h; return cv.u;
}

// ---------------------------------------------------------------------------
// prep_k: demodulated bf16 weight tables [b][uv][o][c] for conv1/3/4/5.
// Grid 768 = 256(conv1) + 128(conv3,beta) + 256(conv4) + 128(conv5,gamma).
// ---------------------------------------------------------------------------
__global__ __launch_bounds__(256) void prep_k(
    const float* __restrict__ w1, const float* __restrict__ mod1,
    const float* __restrict__ w3, const float* __restrict__ mod3,
    const float* __restrict__ beta,
    const float* __restrict__ w4, const float* __restrict__ mod4,
    const float* __restrict__ w5, const float* __restrict__ mod5,
    const float* __restrict__ gam,
    unsigned short* __restrict__ pw1, unsigned short* __restrict__ pw3,
    unsigned short* __restrict__ pw4, unsigned short* __restrict__ pw5)
{
    const int tid = threadIdx.x;
    int blk = blockIdx.x;
    const float* w; const float* mod; const float* rows = nullptr;
    unsigned short* out; int NOUT; int rem;
    if (blk < 256)      { w = w1; mod = mod1; out = pw1; NOUT = 128; rem = blk; }
    else if (blk < 384) { w = w3; mod = mod3; out = pw3; NOUT = 64;  rem = blk - 256; rows = beta; }
    else if (blk < 640) { w = w4; mod = mod4; out = pw4; NOUT = 128; rem = blk - 384; }
    else                { w = w5; mod = mod5; out = pw5; NOUT = 64;  rem = blk - 640; rows = gam;
                          if (out == nullptr) return; }
    const int b = rem / NOUT, o = rem % NOUT;

    __shared__ float mlds[64 * 68];   // [c][uv], pad 68
    __shared__ float wlsh[64];
    __shared__ float red[4 * 64];
    __shared__ float rs[64];

    const float* mbase = mod + ((size_t)(b * NOUT + o) * 64) * 64;  // [c][uv]
#pragma unroll
    for (int k = 0; k < 4; ++k) {
        int l = tid + k * 256;            // float4 index
        float4 vv = ((const float4*)mbase)[l];
        int c = l >> 4, q = l & 15;
        *(float4*)&mlds[c * 68 + q * 4] = vv;
    }
    if (tid < 64) wlsh[tid] = w[o * 64 + tid];
    __syncthreads();

    {
        int uv = tid & 63, part = tid >> 6;
        float ss = 0.f;
#pragma unroll
        for (int j = 0; j < 16; ++j) {
            int c = part * 16 + j;
            float t = wlsh[c] * mlds[c * 68 + uv];
            ss += t * t;
        }
        red[part * 64 + uv] = ss;
    }
    __syncthreads();
    if (tid < 64) {
        float tot = red[tid] + red[64 + tid] + red[128 + tid] + red[192 + tid];
        float rv = rows ? rows[o] : 1.f;
        rs[tid] = rsqrtf(fmaxf(tot, 1e-30f)) * rv;
    }
    __syncthreads();

    {
        int uvw = tid >> 2, cp = tid & 3;
        float r = rs[uvw];
        size_t obase = ((size_t)(b * 64 + uvw) * NOUT + o) * 64;
#pragma unroll
        for (int g = 0; g < 2; ++g) {
            u16x8 pk;
#pragma unroll
            for (int e = 0; e < 8; ++e) {
                int c = cp * 16 + g * 8 + e;
                pk[e] = f2b(wlsh[c] * mlds[c * 68 + uvw] * r);
            }
            *(u16x8*)&out[obase + cp * 16 + g * 8] = pk;
        }
    }
}

// ---------------------------------------------------------------------------
// conv_k: (optional LN / input-scale) -> 1x1 modulated conv GEMM -> gate /
// residual. Staging: thread = (pixel-quad, channel-octet); 8 vector loads;
// LN via shfl_xor over 8 lanes; packed bf16 cvt into LDS [px][ch].
// Grid: (8 chunks of 128px, 64 tiles, NB). Block 256 (4 waves).
// ---------------------------------------------------------------------------
template <int NOUT, bool LN, bool GATE, bool RESID, bool SCALE_IN,
          bool IN_F32, bool RES_F32, bool OUT_F32, bool PREPPED>
__global__ __launch_bounds__(256, 2) void conv_k(
    const void* __restrict__ in_,
    void* __restrict__ out_,
    const unsigned short* __restrict__ pw,   // prepped table
    const float* __restrict__ wb,            // inline fallback
    const float* __restrict__ mod,           // inline fallback
    const float* __restrict__ bias,
    const float* __restrict__ lnw,
    const float* __restrict__ lnb,
    const void* __restrict__ resid_,
    const float* __restrict__ rows,          // beta/gamma
    const float* __restrict__ svec,          // (2,64) for SCALE_IN
    int bbase)
{
    constexpr int CHOUT = GATE ? 64 : NOUT;
    constexpr int PARTS = 256 / NOUT;
    constexpr int CP    = 64 / PARTS;

    const int tid   = threadIdx.x;
    const int chunk = blockIdx.x;
    const int uv    = blockIdx.y;
    const int z     = blockIdx.z;        // local batch (pointer-relative)
    const int bfull = z + bbase;         // absolute batch (pw/mod/svec)
    const int u = uv >> 3, v = uv & 7;
    const int h_base = u * 32 + chunk * 4;
    const int w_base = v * 32;

    __shared__ __align__(16) unsigned short stage[128 * 72];
    __shared__ __align__(16) unsigned short wlds[NOUT * 72];
    __shared__ float sbias[NOUT];
    __shared__ float shP[PREPPED ? 1 : 256];

    // ---- weights ----
    const int o_p  = tid & (NOUT - 1);
    const int part = tid / NOUT;
    float wv[PREPPED ? 1 : CP];
    if constexpr (PREPPED) {
        const unsigned short* pwb = pw + ((size_t)(bfull * 64 + uv) * NOUT) * 64;
#pragma unroll
        for (int k = 0; k < NOUT / 32; ++k) {
            int ci = tid + k * 256;
            *(u16x8*)&wlds[(ci >> 3) * 72 + (ci & 7) * 8] = *(const u16x8*)&pwb[ci * 8];
        }
        if (tid < NOUT) {
            float bs = bias[tid];
            if constexpr (RESID) bs *= rows[tid];
            sbias[tid] = bs;
        }
    } else {
        float ss = 0.f;
#pragma unroll
        for (int j = 0; j < CP; ++j) {
            int c = part * CP + j;
            wv[j] = wb[o_p * 64 + c] * mod[(((bfull * NOUT + o_p) * 64 + c) << 6) + uv];
            ss += wv[j] * wv[j];
        }
        shP[o_p * PARTS + part] = ss;
    }

    // ---- staging: thread = (qd pixel-quad 0..31, cg channel-octet 0..7) ----
    const int cg = tid & 7;
    const int qd = tid >> 3;
    const int c0 = cg * 8;
    const int pixg = (h_base + (qd >> 3)) * 256 + w_base + (qd & 7) * 4;
    float v2[8][4];
#pragma unroll
    for (int k = 0; k < 8; ++k) {
        int idx = ((z * 64 + c0 + k) << 16) + pixg;
        if constexpr (IN_F32) {
            float4 t = *(const float4*)&((const float*)in_)[idx];
            v2[k][0] = t.x; v2[k][1] = t.y; v2[k][2] = t.z; v2[k][3] = t.w;
        } else {
            ushort4 t = *(const ushort4*)&((const unsigned short*)in_)[idx];
            v2[k][0] = b2f(t.x); v2[k][1] = b2f(t.y); v2[k][2] = b2f(t.z); v2[k][3] = b2f(t.w);
        }
    }
    float mu[4], rstd[4];
    if constexpr (LN) {
#pragma unroll
        for (int e = 0; e < 4; ++e) {
            float s1 = 0.f, s2 = 0.f;
#pragma unroll
            for (int k = 0; k < 8; ++k) { s1 += v2[k][e]; s2 += v2[k][e] * v2[k][e]; }
#pragma unroll
            for (int m = 1; m < 8; m <<= 1) {
                s1 += __shfl_xor(s1, m);
                s2 += __shfl_xor(s2, m);
            }
            mu[e] = s1 * (1.f / 64.f);
            float var = s2 * (1.f / 64.f) - mu[e] * mu[e];
            rstd[e] = rsqrtf(fmaxf(var, 0.f) + 1e-6f);
        }
    }
    float lw[8], lb[8], sv[8];
    if constexpr (LN) {
        *(float4*)&lw[0] = *(const float4*)&lnw[c0];
        *(float4*)&lw[4] = *(const float4*)&lnw[c0 + 4];
        *(float4*)&lb[0] = *(const float4*)&lnb[c0];
        *(float4*)&lb[4] = *(const float4*)&lnb[c0 + 4];
    }
    if constexpr (SCALE_IN) {
        *(float4*)&sv[0] = *(const float4*)&svec[bfull * 64 + c0];
        *(float4*)&sv[4] = *(const float4*)&svec[bfull * 64 + c0 + 4];
    }
#pragma unroll
    for (int e = 0; e < 4; ++e) {
        float o8[8];
#pragma unroll
        for (int k = 0; k < 8; ++k) {
            float val = v2[k][e];
            if constexpr (LN) val = (val - mu[e]) * rstd[e] * lw[k] + lb[k];
            if constexpr (SCALE_IN) val *= sv[k];
            o8[k] = val;
        }
        uint4 pk;
        pk.x = pk2(o8[0], o8[1]); pk.y = pk2(o8[2], o8[3]);
        pk.z = pk2(o8[4], o8[5]); pk.w = pk2(o8[6], o8[7]);
        *(uint4*)&stage[(qd * 4 + e) * 72 + c0] = pk;
    }

    __syncthreads();

    if constexpr (!PREPPED) {   // inline weight finalize
        float tot = 0.f;
#pragma unroll
        for (int k = 0; k < PARTS; ++k) tot += shP[o_p * PARTS + k];
        float rn = rsqrtf(fmaxf(tot, 1e-30f));
        float rsv = 1.f;
        if constexpr (RESID) { rsv = rows[o_p]; rn *= rsv; }
#pragma unroll
        for (int j = 0; j < CP; ++j)
            wlds[o_p * 72 + part * CP + j] = f2b(wv[j] * rn);
        if (part == 0) {
            float bs = bias[o_p];
            if constexpr (RESID) bs *= rsv;
            sbias[o_p] = bs;
        }
        __syncthreads();
    }

    // ---- GEMM: M=128 px, N=NOUT, K=64; 16x16x32 bf16 MFMA ----
    const int wave = tid >> 6;
    const int lane = tid & 63;
    const int q = lane >> 4;
    const int r = lane & 15;

    constexpr int NF = (NOUT == 64) ? 1 : 2;
    int nfi[2];
    if constexpr (NOUT == 64)      { nfi[0] = wave;     nfi[1] = wave; }
    else if constexpr (GATE)       { nfi[0] = wave;     nfi[1] = wave + 4; }
    else                           { nfi[0] = 2 * wave; nfi[1] = 2 * wave + 1; }

    bf16x8 bfr[NF][2];
#pragma unroll
    for (int f = 0; f < NF; ++f)
#pragma unroll
        for (int ks = 0; ks < 2; ++ks)
            bfr[f][ks] = *(const bf16x8*)&wlds[(16 * nfi[f] + r) * 72 + ks * 32 + q * 8];

    f32x4 acc[8][NF];
#pragma unroll
    for (int mi = 0; mi < 8; ++mi)
#pragma unroll
        for (int f = 0; f < NF; ++f) acc[mi][f] = (f32x4){0.f, 0.f, 0.f, 0.f};

#pragma unroll
    for (int mi = 0; mi < 8; ++mi) {
        bf16x8 a0 = *(const bf16x8*)&stage[(16 * mi + r) * 72 + q * 8];
        bf16x8 a1 = *(const bf16x8*)&stage[(16 * mi + r) * 72 + 32 + q * 8];
#pragma unroll
        for (int f = 0; f < NF; ++f) {
            acc[mi][f] = __builtin_amdgcn_mfma_f32_16x16x32_bf16(a0, bfr[f][0], acc[mi][f], 0, 0, 0);
            acc[mi][f] = __builtin_amdgcn_mfma_f32_16x16x32_bf16(a1, bfr[f][1], acc[mi][f], 0, 0, 0);
        }
    }

    // ---- epilogue ----
#pragma unroll
    for (int mi = 0; mi < 8; ++mi) {
        int lp0 = 16 * mi + 4 * q;
        int pix = (h_base + (lp0 >> 5)) * 256 + w_base + (lp0 & 31);
        if constexpr (GATE) {
            int o = 16 * wave + r;
            float ba = sbias[o], bg = sbias[o + 64];
            float g0 = (acc[mi][0][0] + ba) * (acc[mi][1][0] + bg);
            float g1 = (acc[mi][0][1] + ba) * (acc[mi][1][1] + bg);
            float g2 = (acc[mi][0][2] + ba) * (acc[mi][1][2] + bg);
            float g3 = (acc[mi][0][3] + ba) * (acc[mi][1][3] + bg);
            int off = ((z * 64 + o) << 16) + pix;
            *(uint2*)&((unsigned short*)out_)[off] =
                make_uint2((unsigned)pk2(g0, g1), (unsigned)pk2(g2, g3));
        } else {
#pragma unroll
            for (int f = 0; f < NF; ++f) {
                int o = 16 * nfi[f] + r;
                float bs = sbias[o];
                float e0 = acc[mi][f][0] + bs, e1 = acc[mi][f][1] + bs;
                float e2 = acc[mi][f][2] + bs, e3 = acc[mi][f][3] + bs;
                int off = ((z * CHOUT + o) << 16) + pix;
                if constexpr (RESID) {
                    if constexpr (RES_F32) {
                        float4 rv = *(const float4*)&((const float*)resid_)[off];
                        e0 += rv.x; e1 += rv.y; e2 += rv.z; e3 += rv.w;
                    } else {
                        ushort4 rv = *(const ushort4*)&((const unsigned short*)resid_)[off];
                        e0 += b2f(rv.x); e1 += b2f(rv.y); e2 += b2f(rv.z); e3 += b2f(rv.w);
                    }
                }
                if constexpr (OUT_F32) {
                    *(float4*)&((float*)out_)[off] = make_float4(e0, e1, e2, e3);
                } else {
                    *(uint2*)&((unsigned short*)out_)[off] =
                        make_uint2((unsigned)pk2(e0, e1), (unsigned)pk2(e2, e3));
                }
            }
        }
    }
}

// ---------------------------------------------------------------------------
// dw_k: depthwise 3x3 modulated + gate + SCA partials. 8 px/thread, direct
// global vector loads, halo via shuffles (image-border zeros).
// Grid: (32 row-bands of 8, 64 oc, NB). Block 256.
// ---------------------------------------------------------------------------
__global__ __launch_bounds__(256, 4) void dw_k(
    const unsigned short* __restrict__ t1,   // (NB,128,H,W) bf16
    unsigned short* __restrict__ t3,         // (NB,64,H,W) bf16
    const float* __restrict__ w2,            // (128,3,3)
    const float* __restrict__ b2,            // (128)
    const float* __restrict__ mod2,          // (2,128,8,8)
    float* __restrict__ s0,                  // (2,64)
    int bbase)
{
    const int tid  = threadIdx.x;
    const int band = blockIdx.x;             // 8 rows
    const int oc   = blockIdx.y;
    const int z    = blockIdx.z;
    const int bfull = z + bbase;
    const int u = band >> 2;                 // tile row

    __shared__ float wl[2][8][9];
    __shared__ float wred[4];

    if (tid < 16) {
        int halfc = tid >> 3, vv = tid & 7;
        const float* wrow = w2 + (oc + halfc * 64) * 9;
        float wloc[9], ssum = 0.f;
#pragma unroll
        for (int k = 0; k < 9; ++k) { wloc[k] = wrow[k]; ssum += wloc[k] * wloc[k]; }
        float m = mod2[(bfull * 128 + oc + halfc * 64) * 64 + u * 8 + vv];
        float rn = m * rsqrtf(fmaxf(m * m * ssum, 1e-30f));
#pragma unroll
        for (int k = 0; k < 9; ++k) wl[halfc][vv][k] = wloc[k] * rn;
    }
    __syncthreads();

    const int strip = tid & 31;              // 8-px strip
    const int row   = band * 8 + (tid >> 5);
    const int v     = strip >> 2;

    float wa[9], wg[9];
#pragma unroll
    for (int k = 0; k < 9; ++k) { wa[k] = wl[0][v][k]; wg[k] = wl[1][v][k]; }
    const float ba = b2[oc], bg = b2[oc + 64];

    const unsigned short* pa = t1 + (((size_t)z * 128 + oc) << 16);
    const unsigned short* pg = pa + ((size_t)64 << 16);

    float fa[3][8], fg[3][8], la[3], ra[3], lg[3], rg[3];
#pragma unroll
    for (int dr = 0; dr < 3; ++dr) {
        int rr = row - 1 + dr;
        if (rr >= 0 && rr < 256) {
            u16x8 va = *(const u16x8*)&pa[rr * 256 + strip * 8];
            u16x8 vg = *(const u16x8*)&pg[rr * 256 + strip * 8];
#pragma unroll
            for (int e = 0; e < 8; ++e) { fa[dr][e] = b2f(va[e]); fg[dr][e] = b2f(vg[e]); }
        } else {
#pragma unroll
            for (int e = 0; e < 8; ++e) { fa[dr][e] = 0.f; fg[dr][e] = 0.f; }
        }
        float t;
        t = __shfl_up(fa[dr][7], 1);   la[dr] = (strip == 0)  ? 0.f : t;
        t = __shfl_up(fg[dr][7], 1);   lg[dr] = (strip == 0)  ? 0.f : t;
        t = __shfl_down(fa[dr][0], 1); ra[dr] = (strip == 31) ? 0.f : t;
        t = __shfl_down(fg[dr][0], 1); rg[dr] = (strip == 31) ? 0.f : t;
    }

    float psum = 0.f;
    u16x8 pk;
#pragma unroll
    for (int j = 0; j < 8; ++j) {
        float a = 0.f, g = 0.f;
#pragma unroll
        for (int dr = 0; dr < 3; ++dr) {
            float m1a = (j == 0) ? la[dr] : fa[dr][j - 1];
            float p1a = (j == 7) ? ra[dr] : fa[dr][j + 1];
            float m1g = (j == 0) ? lg[dr] : fg[dr][j - 1];
            float p1g = (j == 7) ? rg[dr] : fg[dr][j + 1];
            a += wa[dr * 3] * m1a + wa[dr * 3 + 1] * fa[dr][j] + wa[dr * 3 + 2] * p1a;
            g += wg[dr * 3] * m1g + wg[dr * 3 + 1] * fg[dr][j] + wg[dr * 3 + 2] * p1g;
        }
        float val = (a + ba) * (g + bg);
        psum += val;
        pk[j] = f2b(val);
    }
    *(u16x8*)&t3[(((size_t)z * 64 + oc) << 16) + row * 256 + strip * 8] = pk;

    for (int off = 32; off > 0; off >>= 1) psum += __shfl_down(psum, off, 64);
    if ((tid & 63) == 0) wred[tid >> 6] = psum;
    __syncthreads();
    if (tid == 0)
        atomicAdd(&s0[bfull * 64 + oc], wred[0] + wred[1] + wred[2] + wred[3]);
}

// ---------------------------------------------------------------------------
__global__ void sca_k(const float* __restrict__ s0,
                      const float* __restrict__ scaw,
                      const float* __restrict__ scab,
                      float* __restrict__ sfin)
{
    int t = threadIdx.x;
    int b = t >> 6, o = t & 63;
    float acc = 0.f;
#pragma unroll 8
    for (int c = 0; c < 64; ++c)
        acc += scaw[o * 64 + c] * s0[b * 64 + c];
    sfin[b * 64 + o] = acc * (1.f / 65536.f) + scab[o];
}

// ---------------------------------------------------------------------------
extern "C" void kernel_launch(void* const* d_in, const int* in_sizes, int n_in,
                              void* d_out, int out_size, void* d_ws, size_t ws_size,
                              hipStream_t stream) {
    (void)in_sizes; (void)n_in; (void)out_size;
    const float* x    = (const float*)d_in[0];
    const float* w1   = (const float*)d_in[1];
    const float* b1   = (const float*)d_in[2];
    const float* w2   = (const float*)d_in[3];
    const float* b2   = (const float*)d_in[4];
    const float* w3   = (const float*)d_in[5];
    const float* b3   = (const float*)d_in[6];
    const float* scaw = (const float*)d_in[7];
    const float* scab = (const float*)d_in[8];
    const float* w4   = (const float*)d_in[9];
    const float* b4   = (const float*)d_in[10];
    const float* w5   = (const float*)d_in[11];
    const float* b5   = (const float*)d_in[12];
    const float* n1w  = (const float*)d_in[13];
    const float* n1b  = (const float*)d_in[14];
    const float* n2w  = (const float*)d_in[15];
    const float* n2b  = (const float*)d_in[16];
    const float* beta = (const float*)d_in[17];
    const float* gam  = (const float*)d_in[18];
    const float* mod1 = (const float*)d_in[19];
    const float* mod2 = (const float*)d_in[20];
    const float* mod3 = (const float*)d_in[21];
    const float* mod4 = (const float*)d_in[22];
    const float* mod5 = (const float*)d_in[23];

    char* ws = (char*)d_ws;
    float* outf = (float*)d_out;

    const size_t IMGel = (size_t)64 * 65536;       // elems per 64ch image
    const size_t T1B   = (size_t)128 * 65536 * 2;  // t1 bytes per batch (bf16)

    // pw1/pw3/pw4 in d_out TAIL (dead until the final conv5 write).
    const size_t OUTBYTES = 2 * IMGel * 4;               // 33,554,432
    const size_t PWB1 = 2097152, PWB3 = 1048576, PWB4 = 2097152, PWB5 = 1048576;
    char* pwbase = (char*)d_out + OUTBYTES - (PWB1 + PWB3 + PWB4);
    unsigned short* pw1 = (unsigned short*)pwbase;
    unsigned short* pw3 = (unsigned short*)(pwbase + PWB1);
    unsigned short* pw4 = (unsigned short*)(pwbase + PWB1 + PWB3);

    const size_t needA = 2 * T1B + 4096;
    const bool planA = ws_size >= needA;
    const size_t NBT = planA ? 2 : 1;
    // pw5 lives in d_ws beyond the stats block, if it fits.
    const bool havePw5 = ws_size >= NBT * T1B + 4096 + PWB5;
    char* statb = ws + NBT * T1B;
    float* s0   = (float*)statb;
    float* sfin = (float*)(statb + 512);
    unsigned short* pw5 = havePw5 ? (unsigned short*)(statb + 4096) : nullptr;

    dim3 blk(256);

    hipMemsetAsync(s0, 0, 512, stream);
    prep_k<<<768, blk, 0, stream>>>(w1, mod1, w3, mod3, beta, w4, mod4,
                                    w5, mod5, gam, pw1, pw3, pw4, pw5);

    if (planA) {
        unsigned short* t1 = (unsigned short*)ws;
        unsigned short* y1 = (unsigned short*)ws;
        unsigned short* t4 = (unsigned short*)(ws + 2 * IMGel * 2);
        unsigned short* t3 = (unsigned short*)d_out;          // [0, 16.78MB)

        dim3 gconv(8, 64, 2), gdw(32, 64, 2);

        conv_k<128, true, false, false, false, true, false, false, true>
            <<<gconv, blk, 0, stream>>>(x, t1, pw1, nullptr, nullptr, b1,
                                        n1w, n1b, nullptr, nullptr, nullptr, 0);
        dw_k<<<gdw, blk, 0, stream>>>(t1, t3, w2, b2, mod2, s0, 0);
        sca_k<<<1, 128, 0, stream>>>(s0, scaw, scab, sfin);
        conv_k<64, false, false, true, true, false, true, false, true>
            <<<gconv, blk, 0, stream>>>(t3, y1, pw3, nullptr, nullptr, b3,
                                        nullptr, nullptr, x, beta, sfin, 0);
        conv_k<128, true, true, false, false, false, false, false, true>
            <<<gconv, blk, 0, stream>>>(y1, t4, pw4, nullptr, nullptr, b4,
                                        n2w, n2b, nullptr, nullptr, nullptr, 0);
        if (havePw5) {
            conv_k<64, false, false, true, false, false, false, true, true>
                <<<gconv, blk, 0, stream>>>(t4, outf, pw5, nullptr, nullptr, b5,
                                            nullptr, nullptr, y1, gam, nullptr, 0);
        } else {
            conv_k<64, false, false, true, false, false, false, true, false>
                <<<gconv, blk, 0, stream>>>(t4, outf, nullptr, w5, mod5, b5,
                                            nullptr, nullptr, y1, gam, nullptr, 0);
        }
    } else {
        for (int bb = 0; bb < 2; ++bb) {
            const float* x_b   = x    + (size_t)bb * IMGel;
            float*       out_b = outf + (size_t)bb * IMGel;

            unsigned short* t1 = (unsigned short*)ws;
            unsigned short* y1 = (unsigned short*)ws;
            unsigned short* t4 = (unsigned short*)(ws + IMGel * 2);
            unsigned short* t3 = (unsigned short*)out_b;

            dim3 gconv(8, 64, 1), gdw(32, 64, 1);

            conv_k<128, true, false, false, false, true, false, false, true>
                <<<gconv, blk, 0, stream>>>(x_b, t1, pw1, nullptr, nullptr, b1,
                                            n1w, n1b, nullptr, nullptr, nullptr, bb);
            dw_k<<<gdw, blk, 0, stream>>>(t1, t3, w2, b2, mod2, s0, bb);
            sca_k<<<1, 128, 0, stream>>>(s0, scaw, scab, sfin);
            conv_k<64, false, false, true, true, false, true, false, true>
                <<<gconv, blk, 0, stream>>>(t3, y1, pw3, nullptr, nullptr, b3,
                                            nullptr, nullptr, x_b, beta, sfin, bb);
            conv_k<128, true, true, false, false, false, false, false, true>
                <<<gconv, blk, 0, stream>>>(y1, t4, pw4, nullptr, nullptr, b4,
                                            n2w, n2b, nullptr, nullptr, nullptr, bb);
            if (havePw5) {
                conv_k<64, false, false, true, false, false, false, true, true>
                    <<<gconv, blk, 0, stream>>>(t4, out_b, pw5, nullptr, nullptr, b5,
                                                nullptr, nullptr, y1, gam, nullptr, bb);
            } else {
                conv_k<64, false, false, true, false, false, false, true, false>
                    <<<gconv, blk, 0, stream>>>(t4, out_b, nullptr, w5, mod5, b5,
                                                nullptr, nullptr, y1, gam, nullptr, bb);
            }
        }
    }
}

// Round 7
// 202.855 us; speedup vs baseline: 1.6634x; 1.1127x over previous
//
#include <hip/hip_runtime.h>
#include <hip/hip_bf16.h>

// ---------------------------------------------------------------------------
// NAFNet-like block, MI355X (gfx950). B=2,C=64,H=W=256,DW=128,FFN=128,GRID=8.
// fp32 true inputs + fp32 output; bf16 intermediates; MFMA 16x16x32 bf16.
// R6: tail fusion conv3+LN2+conv4+gate+conv5 in one kernel (y1/t4 never hit
//     HBM); weight B-frags loaded straight from prepped tables (no wlds LDS,
//     one less barrier); t3 moved to d_ws. 6 dispatches total.
// ---------------------------------------------------------------------------

typedef __bf16 bf16x8 __attribute__((ext_vector_type(8)));
typedef float f32x4 __attribute__((ext_vector_type(4)));
typedef unsigned short u16x8 __attribute__((ext_vector_type(8)));

__device__ __forceinline__ float b2f(unsigned short u) {
    union { unsigned int i; float f; } x; x.i = ((unsigned int)u) << 16; return x.f;
}
__device__ __forceinline__ unsigned short f2b(float f) {
    union { float f; unsigned int i; } x; x.f = f;
    unsigned int i = x.i;
    return (unsigned short)((i + 0x7FFFu + ((i >> 16) & 1u)) >> 16);  // RNE
}
__device__ __forceinline__ unsigned int pk2(float a, float b) {
    __hip_bfloat162 h = __float22bfloat162_rn(float2{a, b});  // v_cvt_pk_bf16_f32
    union { __hip_bfloat162 h; unsigned int u; } cv; cv.h = h; return cv.u;
}

// ---------------------------------------------------------------------------
// prep_k: demodulated bf16 weight tables [b][uv][o][c] for conv1/3/4/5.
// Grid 768 = 256(conv1) + 128(conv3,beta) + 256(conv4) + 128(conv5,gamma).
// ---------------------------------------------------------------------------
__global__ __launch_bounds__(256) void prep_k(
    const float* __restrict__ w1, const float* __restrict__ mod1,
    const float* __restrict__ w3, const float* __restrict__ mod3,
    const float* __restrict__ beta,
    const float* __restrict__ w4, const float* __restrict__ mod4,
    const float* __restrict__ w5, const float* __restrict__ mod5,
    const float* __restrict__ gam,
    unsigned short* __restrict__ pw1, unsigned short* __restrict__ pw3,
    unsigned short* __restrict__ pw4, unsigned short* __restrict__ pw5)
{
    const int tid = threadIdx.x;
    int blk = blockIdx.x;
    const float* w; const float* mod; const float* rows = nullptr;
    unsigned short* out; int NOUT; int rem;
    if (blk < 256)      { w = w1; mod = mod1; out = pw1; NOUT = 128; rem = blk; }
    else if (blk < 384) { w = w3; mod = mod3; out = pw3; NOUT = 64;  rem = blk - 256; rows = beta; }
    else if (blk < 640) { w = w4; mod = mod4; out = pw4; NOUT = 128; rem = blk - 384; }
    else                { w = w5; mod = mod5; out = pw5; NOUT = 64;  rem = blk - 640; rows = gam; }
    const int b = rem / NOUT, o = rem % NOUT;

    __shared__ float mlds[64 * 68];   // [c][uv], pad 68
    __shared__ float wlsh[64];
    __shared__ float red[4 * 64];
    __shared__ float rs[64];

    const float* mbase = mod + ((size_t)(b * NOUT + o) * 64) * 64;  // [c][uv]
#pragma unroll
    for (int k = 0; k < 4; ++k) {
        int l = tid + k * 256;            // float4 index
        float4 vv = ((const float4*)mbase)[l];
        int c = l >> 4, q = l & 15;
        *(float4*)&mlds[c * 68 + q * 4] = vv;
    }
    if (tid < 64) wlsh[tid] = w[o * 64 + tid];
    __syncthreads();

    {
        int uv = tid & 63, part = tid >> 6;
        float ss = 0.f;
#pragma unroll
        for (int j = 0; j < 16; ++j) {
            int c = part * 16 + j;
            float t = wlsh[c] * mlds[c * 68 + uv];
            ss += t * t;
        }
        red[part * 64 + uv] = ss;
    }
    __syncthreads();
    if (tid < 64) {
        float tot = red[tid] + red[64 + tid] + red[128 + tid] + red[192 + tid];
        float rv = rows ? rows[tid == tid ? o : o] : 1.f;
        rs[tid] = rsqrtf(fmaxf(tot, 1e-30f)) * (rows ? rows[o] : 1.f) * (rv == rv ? 1.f : 1.f);
    }
    __syncthreads();

    {
        int uvw = tid >> 2, cp = tid & 3;
        float r = rs[uvw];
        size_t obase = ((size_t)(b * 64 + uvw) * NOUT + o) * 64;
#pragma unroll
        for (int g = 0; g < 2; ++g) {
            u16x8 pk;
#pragma unroll
            for (int e = 0; e < 8; ++e) {
                int c = cp * 16 + g * 8 + e;
                pk[e] = f2b(wlsh[c] * mlds[c * 68 + uvw] * r);
            }
            *(u16x8*)&out[obase + cp * 16 + g * 8] = pk;
        }
    }
}

// ---------------------------------------------------------------------------
// head_k: LN1 + conv1 (64->128). x fp32 -> t1 bf16. Weight frags direct from
// pw1. Grid (8,64,NB), block 256.
// ---------------------------------------------------------------------------
__global__ __launch_bounds__(256, 2) void head_k(
    const float* __restrict__ x, unsigned short* __restrict__ t1,
    const unsigned short* __restrict__ pw1, const float* __restrict__ b1,
    const float* __restrict__ n1w, const float* __restrict__ n1b, int bbase)
{
    const int tid   = threadIdx.x;
    const int chunk = blockIdx.x;
    const int uv    = blockIdx.y;
    const int z     = blockIdx.z;
    const int bfull = z + bbase;
    const int u = uv >> 3, v = uv & 7;
    const int h_base = u * 32 + chunk * 4;
    const int w_base = v * 32;

    __shared__ __align__(16) unsigned short stage[128 * 72];

    const int wave = tid >> 6;
    const int lane = tid & 63;
    const int q = lane >> 4;
    const int r = lane & 15;
    const int nfi[2] = {2 * wave, 2 * wave + 1};

    // B-frags + biases straight from global (L2-resident tables)
    const unsigned short* pwt = pw1 + ((size_t)(bfull * 64 + uv) * 128) * 64;
    bf16x8 bfr[2][2];
#pragma unroll
    for (int f = 0; f < 2; ++f)
#pragma unroll
        for (int ks = 0; ks < 2; ++ks)
            bfr[f][ks] = *(const bf16x8*)&pwt[(16 * nfi[f] + r) * 64 + ks * 32 + q * 8];
    float bsc[2] = {b1[16 * nfi[0] + r], b1[16 * nfi[1] + r]};

    // staging: thread = (pixel-quad qd, channel-octet cg); LN via shfl_xor
    const int cg = tid & 7;
    const int qd = tid >> 3;
    const int c0 = cg * 8;
    const int pixg = (h_base + (qd >> 3)) * 256 + w_base + (qd & 7) * 4;
    float v2[8][4];
#pragma unroll
    for (int k = 0; k < 8; ++k) {
        float4 t = *(const float4*)&x[((z * 64 + c0 + k) << 16) + pixg];
        v2[k][0] = t.x; v2[k][1] = t.y; v2[k][2] = t.z; v2[k][3] = t.w;
    }
    float lw[8], lb[8];
    *(float4*)&lw[0] = *(const float4*)&n1w[c0];
    *(float4*)&lw[4] = *(const float4*)&n1w[c0 + 4];
    *(float4*)&lb[0] = *(const float4*)&n1b[c0];
    *(float4*)&lb[4] = *(const float4*)&n1b[c0 + 4];
#pragma unroll
    for (int e = 0; e < 4; ++e) {
        float s1 = 0.f, s2 = 0.f;
#pragma unroll
        for (int k = 0; k < 8; ++k) { s1 += v2[k][e]; s2 += v2[k][e] * v2[k][e]; }
#pragma unroll
        for (int m = 1; m < 8; m <<= 1) { s1 += __shfl_xor(s1, m); s2 += __shfl_xor(s2, m); }
        float mu = s1 * (1.f / 64.f);
        float var = s2 * (1.f / 64.f) - mu * mu;
        float rstd = rsqrtf(fmaxf(var, 0.f) + 1e-6f);
        float o8[8];
#pragma unroll
        for (int k = 0; k < 8; ++k) o8[k] = (v2[k][e] - mu) * rstd * lw[k] + lb[k];
        uint4 pk;
        pk.x = pk2(o8[0], o8[1]); pk.y = pk2(o8[2], o8[3]);
        pk.z = pk2(o8[4], o8[5]); pk.w = pk2(o8[6], o8[7]);
        *(uint4*)&stage[(qd * 4 + e) * 72 + c0] = pk;
    }

    __syncthreads();

    f32x4 acc[8][2];
#pragma unroll
    for (int mi = 0; mi < 8; ++mi) { acc[mi][0] = (f32x4){0,0,0,0}; acc[mi][1] = (f32x4){0,0,0,0}; }
#pragma unroll
    for (int mi = 0; mi < 8; ++mi) {
        bf16x8 a0 = *(const bf16x8*)&stage[(16 * mi + r) * 72 + q * 8];
        bf16x8 a1 = *(const bf16x8*)&stage[(16 * mi + r) * 72 + 32 + q * 8];
#pragma unroll
        for (int f = 0; f < 2; ++f) {
            acc[mi][f] = __builtin_amdgcn_mfma_f32_16x16x32_bf16(a0, bfr[f][0], acc[mi][f], 0, 0, 0);
            acc[mi][f] = __builtin_amdgcn_mfma_f32_16x16x32_bf16(a1, bfr[f][1], acc[mi][f], 0, 0, 0);
        }
    }

#pragma unroll
    for (int mi = 0; mi < 8; ++mi) {
        int lp0 = 16 * mi + 4 * q;
        int pix = (h_base + (lp0 >> 5)) * 256 + w_base + (lp0 & 31);
#pragma unroll
        for (int f = 0; f < 2; ++f) {
            int o = 16 * nfi[f] + r;
            float bs = bsc[f];
            *(uint2*)&t1[((z * 128 + o) << 16) + pix] =
                make_uint2(pk2(acc[mi][f][0] + bs, acc[mi][f][1] + bs),
                           pk2(acc[mi][f][2] + bs, acc[mi][f][3] + bs));
        }
    }
}

// ---------------------------------------------------------------------------
// tail_k: conv3(+s,+beta,+x resid) -> y1 -> LN2 -> conv4 -> gate -> conv5
// (+gamma) -> out = y1 + z*gamma. One 128-px tile per block; y1/z never
// leave the block. Grid (8,64,NB), block 256.
// ---------------------------------------------------------------------------
__global__ __launch_bounds__(256, 2) void tail_k(
    const unsigned short* __restrict__ t3, const float* __restrict__ x,
    float* __restrict__ outp,
    const unsigned short* __restrict__ pw3, const float* __restrict__ b3,
    const float* __restrict__ beta,
    const unsigned short* __restrict__ pw4, const float* __restrict__ b4,
    const float* __restrict__ n2w, const float* __restrict__ n2b,
    const unsigned short* __restrict__ pw5, const float* __restrict__ b5,
    const float* __restrict__ gam,
    const float* __restrict__ svec, int bbase)
{
    const int tid   = threadIdx.x;
    const int chunk = blockIdx.x;
    const int uv    = blockIdx.y;
    const int z     = blockIdx.z;
    const int bfull = z + bbase;
    const int u = uv >> 3, v = uv & 7;
    const int h_base = u * 32 + chunk * 4;
    const int w_base = v * 32;

    __shared__ __align__(16) unsigned short stage[128 * 72];

    const int wave = tid >> 6;
    const int lane = tid & 63;
    const int q = lane >> 4;
    const int r = lane & 15;
    const int oo = 16 * wave + r;          // this thread's out-channel (64-wide GEMMs)

    // ---- weight frags + per-lane scalars (global, L2) ----
    const unsigned short* p3 = pw3 + (size_t)(bfull * 64 + uv) * 64 * 64;
    const unsigned short* p4 = pw4 + (size_t)(bfull * 64 + uv) * 128 * 64;
    const unsigned short* p5 = pw5 + (size_t)(bfull * 64 + uv) * 64 * 64;
    bf16x8 w3f[2], w5f[2], w4f[2][2];
    const int nfi4[2] = {wave, wave + 4};  // gate pairs (o, o+64)
#pragma unroll
    for (int ks = 0; ks < 2; ++ks) {
        w3f[ks] = *(const bf16x8*)&p3[(oo) * 64 + ks * 32 + q * 8];
        w5f[ks] = *(const bf16x8*)&p5[(oo) * 64 + ks * 32 + q * 8];
#pragma unroll
        for (int f = 0; f < 2; ++f)
            w4f[f][ks] = *(const bf16x8*)&p4[(16 * nfi4[f] + r) * 64 + ks * 32 + q * 8];
    }
    const float sb3 = b3[oo] * beta[oo];
    const float ba4 = b4[oo], bg4 = b4[oo + 64];
    const float sb5 = b5[oo] * gam[oo];

    // ---- stage t3 (bf16) with svec fold ----
    const int cg = tid & 7;
    const int qd = tid >> 3;
    const int c0 = cg * 8;
    const int pixg = (h_base + (qd >> 3)) * 256 + w_base + (qd & 7) * 4;
    {
        float sv[8];
        *(float4*)&sv[0] = *(const float4*)&svec[bfull * 64 + c0];
        *(float4*)&sv[4] = *(const float4*)&svec[bfull * 64 + c0 + 4];
        float v2[8][4];
#pragma unroll
        for (int k = 0; k < 8; ++k) {
            ushort4 t = *(const ushort4*)&t3[((z * 64 + c0 + k) << 16) + pixg];
            v2[k][0] = b2f(t.x) * sv[k]; v2[k][1] = b2f(t.y) * sv[k];
            v2[k][2] = b2f(t.z) * sv[k]; v2[k][3] = b2f(t.w) * sv[k];
        }
#pragma unroll
        for (int e = 0; e < 4; ++e) {
            uint4 pk;
            pk.x = pk2(v2[0][e], v2[1][e]); pk.y = pk2(v2[2][e], v2[3][e]);
            pk.z = pk2(v2[4][e], v2[5][e]); pk.w = pk2(v2[6][e], v2[7][e]);
            *(uint4*)&stage[(qd * 4 + e) * 72 + c0] = pk;
        }
    }
    __syncthreads();

    // ---- GEMM3: y = conv3(t3*s) (beta folded in pw3) ----
    f32x4 acc3[8];
#pragma unroll
    for (int mi = 0; mi < 8; ++mi) acc3[mi] = (f32x4){0, 0, 0, 0};
#pragma unroll
    for (int mi = 0; mi < 8; ++mi) {
        bf16x8 a0 = *(const bf16x8*)&stage[(16 * mi + r) * 72 + q * 8];
        bf16x8 a1 = *(const bf16x8*)&stage[(16 * mi + r) * 72 + 32 + q * 8];
        acc3[mi] = __builtin_amdgcn_mfma_f32_16x16x32_bf16(a0, w3f[0], acc3[mi], 0, 0, 0);
        acc3[mi] = __builtin_amdgcn_mfma_f32_16x16x32_bf16(a1, w3f[1], acc3[mi], 0, 0, 0);
    }
    __syncthreads();   // all stage reads done before overwrite

    // ---- y1 = x + conv3 result (fp32 in regs) ----
    float y1v[8][4];
#pragma unroll
    for (int mi = 0; mi < 8; ++mi) {
        int lp0 = 16 * mi + 4 * q;
        int pix = (h_base + (lp0 >> 5)) * 256 + w_base + (lp0 & 31);
        float4 xr = *(const float4*)&x[((z * 64 + oo) << 16) + pix];
        y1v[mi][0] = acc3[mi][0] + sb3 + xr.x;
        y1v[mi][1] = acc3[mi][1] + sb3 + xr.y;
        y1v[mi][2] = acc3[mi][2] + sb3 + xr.z;
        y1v[mi][3] = acc3[mi][3] + sb3 + xr.w;
    }
    // write y1 (bf16) to stage [px][ch]
#pragma unroll
    for (int mi = 0; mi < 8; ++mi)
#pragma unroll
        for (int e = 0; e < 4; ++e)
            stage[(16 * mi + 4 * q + e) * 72 + oo] = f2b(y1v[mi][e]);
    __syncthreads();

    // ---- LN2 in-place on stage ----
    {
        float lw[8], lb[8];
        *(float4*)&lw[0] = *(const float4*)&n2w[c0];
        *(float4*)&lw[4] = *(const float4*)&n2w[c0 + 4];
        *(float4*)&lb[0] = *(const float4*)&n2b[c0];
        *(float4*)&lb[4] = *(const float4*)&n2b[c0 + 4];
#pragma unroll
        for (int e = 0; e < 4; ++e) {
            int px = qd * 4 + e;
            uint4 raw = *(const uint4*)&stage[px * 72 + c0];
            unsigned short* rp = (unsigned short*)&raw;
            float vv[8];
            float s1 = 0.f, s2 = 0.f;
#pragma unroll
            for (int k = 0; k < 8; ++k) { vv[k] = b2f(rp[k]); s1 += vv[k]; s2 += vv[k] * vv[k]; }
#pragma unroll
            for (int m = 1; m < 8; m <<= 1) { s1 += __shfl_xor(s1, m); s2 += __shfl_xor(s2, m); }
            float mu = s1 * (1.f / 64.f);
            float var = s2 * (1.f / 64.f) - mu * mu;
            float rstd = rsqrtf(fmaxf(var, 0.f) + 1e-6f);
            float o8[8];
#pragma unroll
            for (int k = 0; k < 8; ++k) o8[k] = (vv[k] - mu) * rstd * lw[k] + lb[k];
            uint4 pk;
            pk.x = pk2(o8[0], o8[1]); pk.y = pk2(o8[2], o8[3]);
            pk.z = pk2(o8[4], o8[5]); pk.w = pk2(o8[6], o8[7]);
            *(uint4*)&stage[px * 72 + c0] = pk;
        }
    }
    __syncthreads();

    // ---- GEMM4 (64->128) + gate ----
    f32x4 acc4[8][2];
#pragma unroll
    for (int mi = 0; mi < 8; ++mi) { acc4[mi][0] = (f32x4){0,0,0,0}; acc4[mi][1] = (f32x4){0,0,0,0}; }
#pragma unroll
    for (int mi = 0; mi < 8; ++mi) {
        bf16x8 a0 = *(const bf16x8*)&stage[(16 * mi + r) * 72 + q * 8];
        bf16x8 a1 = *(const bf16x8*)&stage[(16 * mi + r) * 72 + 32 + q * 8];
#pragma unroll
        for (int f = 0; f < 2; ++f) {
            acc4[mi][f] = __builtin_amdgcn_mfma_f32_16x16x32_bf16(a0, w4f[f][0], acc4[mi][f], 0, 0, 0);
            acc4[mi][f] = __builtin_amdgcn_mfma_f32_16x16x32_bf16(a1, w4f[f][1], acc4[mi][f], 0, 0, 0);
        }
    }
    __syncthreads();   // stage reads done
#pragma unroll
    for (int mi = 0; mi < 8; ++mi)
#pragma unroll
        for (int e = 0; e < 4; ++e) {
            float zv = (acc4[mi][0][e] + ba4) * (acc4[mi][1][e] + bg4);
            stage[(16 * mi + 4 * q + e) * 72 + oo] = f2b(zv);
        }
    __syncthreads();

    // ---- GEMM5 (64->64, gamma folded) + final residual ----
    f32x4 acc5[8];
#pragma unroll
    for (int mi = 0; mi < 8; ++mi) acc5[mi] = (f32x4){0, 0, 0, 0};
#pragma unroll
    for (int mi = 0; mi < 8; ++mi) {
        bf16x8 a0 = *(const bf16x8*)&stage[(16 * mi + r) * 72 + q * 8];
        bf16x8 a1 = *(const bf16x8*)&stage[(16 * mi + r) * 72 + 32 + q * 8];
        acc5[mi] = __builtin_amdgcn_mfma_f32_16x16x32_bf16(a0, w5f[0], acc5[mi], 0, 0, 0);
        acc5[mi] = __builtin_amdgcn_mfma_f32_16x16x32_bf16(a1, w5f[1], acc5[mi], 0, 0, 0);
    }
#pragma unroll
    for (int mi = 0; mi < 8; ++mi) {
        int lp0 = 16 * mi + 4 * q;
        int pix = (h_base + (lp0 >> 5)) * 256 + w_base + (lp0 & 31);
        *(float4*)&outp[((z * 64 + oo) << 16) + pix] =
            make_float4(y1v[mi][0] + acc5[mi][0] + sb5,
                        y1v[mi][1] + acc5[mi][1] + sb5,
                        y1v[mi][2] + acc5[mi][2] + sb5,
                        y1v[mi][3] + acc5[mi][3] + sb5);
    }
}

// ---------------------------------------------------------------------------
// dw_k: depthwise 3x3 modulated + gate + SCA partials. 8 px/thread, direct
// global vector loads, halo via shuffles (image-border zeros).
// Grid: (32 row-bands of 8, 64 oc, NB). Block 256.
// ---------------------------------------------------------------------------
__global__ __launch_bounds__(256, 4) void dw_k(
    const unsigned short* __restrict__ t1,   // (NB,128,H,W) bf16
    unsigned short* __restrict__ t3,         // (NB,64,H,W) bf16
    const float* __restrict__ w2,            // (128,3,3)
    const float* __restrict__ b2,            // (128)
    const float* __restrict__ mod2,          // (2,128,8,8)
    float* __restrict__ s0,                  // (2,64)
    int bbase)
{
    const int tid  = threadIdx.x;
    const int band = blockIdx.x;
    const int oc   = blockIdx.y;
    const int z    = blockIdx.z;
    const int bfull = z + bbase;
    const int u = band >> 2;

    __shared__ float wl[2][8][9];
    __shared__ float wred[4];

    if (tid < 16) {
        int halfc = tid >> 3, vv = tid & 7;
        const float* wrow = w2 + (oc + halfc * 64) * 9;
        float wloc[9], ssum = 0.f;
#pragma unroll
        for (int k = 0; k < 9; ++k) { wloc[k] = wrow[k]; ssum += wloc[k] * wloc[k]; }
        float m = mod2[(bfull * 128 + oc + halfc * 64) * 64 + u * 8 + vv];
        float rn = m * rsqrtf(fmaxf(m * m * ssum, 1e-30f));
#pragma unroll
        for (int k = 0; k < 9; ++k) wl[halfc][vv][k] = wloc[k] * rn;
    }
    __syncthreads();

    const int strip = tid & 31;
    const int row   = band * 8 + (tid >> 5);
    const int v     = strip >> 2;

    float wa[9], wg[9];
#pragma unroll
    for (int k = 0; k < 9; ++k) { wa[k] = wl[0][v][k]; wg[k] = wl[1][v][k]; }
    const float ba = b2[oc], bg = b2[oc + 64];

    const unsigned short* pa = t1 + (((size_t)z * 128 + oc) << 16);
    const unsigned short* pg = pa + ((size_t)64 << 16);

    float fa[3][8], fg[3][8], la[3], ra[3], lg[3], rg[3];
#pragma unroll
    for (int dr = 0; dr < 3; ++dr) {
        int rr = row - 1 + dr;
        if (rr >= 0 && rr < 256) {
            u16x8 va = *(const u16x8*)&pa[rr * 256 + strip * 8];
            u16x8 vg = *(const u16x8*)&pg[rr * 256 + strip * 8];
#pragma unroll
            for (int e = 0; e < 8; ++e) { fa[dr][e] = b2f(va[e]); fg[dr][e] = b2f(vg[e]); }
        } else {
#pragma unroll
            for (int e = 0; e < 8; ++e) { fa[dr][e] = 0.f; fg[dr][e] = 0.f; }
        }
        float t;
        t = __shfl_up(fa[dr][7], 1);   la[dr] = (strip == 0)  ? 0.f : t;
        t = __shfl_up(fg[dr][7], 1);   lg[dr] = (strip == 0)  ? 0.f : t;
        t = __shfl_down(fa[dr][0], 1); ra[dr] = (strip == 31) ? 0.f : t;
        t = __shfl_down(fg[dr][0], 1); rg[dr] = (strip == 31) ? 0.f : t;
    }

    float psum = 0.f;
    u16x8 pk;
#pragma unroll
    for (int j = 0; j < 8; ++j) {
        float a = 0.f, g = 0.f;
#pragma unroll
        for (int dr = 0; dr < 3; ++dr) {
            float m1a = (j == 0) ? la[dr] : fa[dr][j - 1];
            float p1a = (j == 7) ? ra[dr] : fa[dr][j + 1];
            float m1g = (j == 0) ? lg[dr] : fg[dr][j - 1];
            float p1g = (j == 7) ? rg[dr] : fg[dr][j + 1];
            a += wa[dr * 3] * m1a + wa[dr * 3 + 1] * fa[dr][j] + wa[dr * 3 + 2] * p1a;
            g += wg[dr * 3] * m1g + wg[dr * 3 + 1] * fg[dr][j] + wg[dr * 3 + 2] * p1g;
        }
        float val = (a + ba) * (g + bg);
        psum += val;
        pk[j] = f2b(val);
    }
    *(u16x8*)&t3[(((size_t)z * 64 + oc) << 16) + row * 256 + strip * 8] = pk;

    for (int off = 32; off > 0; off >>= 1) psum += __shfl_down(psum, off, 64);
    if ((tid & 63) == 0) wred[tid >> 6] = psum;
    __syncthreads();
    if (tid == 0)
        atomicAdd(&s0[bfull * 64 + oc], wred[0] + wred[1] + wred[2] + wred[3]);
}

// ---------------------------------------------------------------------------
__global__ void sca_k(const float* __restrict__ s0,
                      const float* __restrict__ scaw,
                      const float* __restrict__ scab,
                      float* __restrict__ sfin)
{
    int t = threadIdx.x;
    int b = t >> 6, o = t & 63;
    float acc = 0.f;
#pragma unroll 8
    for (int c = 0; c < 64; ++c)
        acc += scaw[o * 64 + c] * s0[b * 64 + c];
    sfin[b * 64 + o] = acc * (1.f / 65536.f) + scab[o];
}

// ---------------------------------------------------------------------------
extern "C" void kernel_launch(void* const* d_in, const int* in_sizes, int n_in,
                              void* d_out, int out_size, void* d_ws, size_t ws_size,
                              hipStream_t stream) {
    (void)in_sizes; (void)n_in; (void)out_size;
    const float* x    = (const float*)d_in[0];
    const float* w1   = (const float*)d_in[1];
    const float* b1   = (const float*)d_in[2];
    const float* w2   = (const float*)d_in[3];
    const float* b2   = (const float*)d_in[4];
    const float* w3   = (const float*)d_in[5];
    const float* b3   = (const float*)d_in[6];
    const float* scaw = (const float*)d_in[7];
    const float* scab = (const float*)d_in[8];
    const float* w4   = (const float*)d_in[9];
    const float* b4   = (const float*)d_in[10];
    const float* w5   = (const float*)d_in[11];
    const float* b5   = (const float*)d_in[12];
    const float* n1w  = (const float*)d_in[13];
    const float* n1b  = (const float*)d_in[14];
    const float* n2w  = (const float*)d_in[15];
    const float* n2b  = (const float*)d_in[16];
    const float* beta = (const float*)d_in[17];
    const float* gam  = (const float*)d_in[18];
    const float* mod1 = (const float*)d_in[19];
    const float* mod2 = (const float*)d_in[20];
    const float* mod3 = (const float*)d_in[21];
    const float* mod4 = (const float*)d_in[22];
    const float* mod5 = (const float*)d_in[23];

    char* ws = (char*)d_ws;
    float* outf = (float*)d_out;

    const size_t IMGel = (size_t)64 * 65536;
    const size_t T1B   = (size_t)128 * 65536 * 2;   // 16.78 MB per batch
    const size_t T3B   = (size_t)64 * 65536 * 2;    // 8.39 MB per batch
    const size_t PW1B = 2097152, PW3B = 1048576, PW4B = 2097152, PW5B = 1048576;
    const size_t TBLB = PW1B + PW3B + PW4B + PW5B;  // 6.29 MB

    const size_t needA = 2 * (T1B + T3B) + 4096 + TBLB;   // ~56.6 MB
    const bool planA = ws_size >= needA;                  // ws measured ~268 MB
    const size_t NBT = planA ? 2 : 1;

    unsigned short* t1 = (unsigned short*)ws;
    unsigned short* t3 = (unsigned short*)(ws + NBT * T1B);
    char* statb = ws + NBT * (T1B + T3B);
    float* s0   = (float*)statb;
    float* sfin = (float*)(statb + 512);
    unsigned short* pw1 = (unsigned short*)(statb + 4096);
    unsigned short* pw3 = (unsigned short*)(statb + 4096 + PW1B);
    unsigned short* pw4 = (unsigned short*)(statb + 4096 + PW1B + PW3B);
    unsigned short* pw5 = (unsigned short*)(statb + 4096 + PW1B + PW3B + PW4B);

    dim3 blk(256);

    hipMemsetAsync(s0, 0, 512, stream);
    prep_k<<<768, blk, 0, stream>>>(w1, mod1, w3, mod3, beta, w4, mod4,
                                    w5, mod5, gam, pw1, pw3, pw4, pw5);

    if (planA) {
        dim3 gconv(8, 64, 2), gdw(32, 64, 2);
        head_k<<<gconv, blk, 0, stream>>>(x, t1, pw1, b1, n1w, n1b, 0);
        dw_k<<<gdw, blk, 0, stream>>>(t1, t3, w2, b2, mod2, s0, 0);
        sca_k<<<1, 128, 0, stream>>>(s0, scaw, scab, sfin);
        tail_k<<<gconv, blk, 0, stream>>>(t3, x, outf, pw3, b3, beta,
                                          pw4, b4, n2w, n2b, pw5, b5, gam,
                                          sfin, 0);
    } else {
        for (int bb = 0; bb < 2; ++bb) {
            const float* x_b   = x    + (size_t)bb * IMGel;
            float*       out_b = outf + (size_t)bb * IMGel;
            dim3 gconv(8, 64, 1), gdw(32, 64, 1);
            head_k<<<gconv, blk, 0, stream>>>(x_b, t1, pw1, b1, n1w, n1b, bb);
            dw_k<<<gdw, blk, 0, stream>>>(t1, t3, w2, b2, mod2, s0, bb);
            sca_k<<<1, 128, 0, stream>>>(s0, scaw, scab, sfin);
            tail_k<<<gconv, blk, 0, stream>>>(t3, x_b, out_b, pw3, b3, beta,
                                              pw4, b4, n2w, n2b, pw5, b5, gam,
                                              sfin, bb);
        }
    }
}